// Round 4
// baseline (290.074 us; speedup 1.0000x reference)
//
#include <hip/hip_runtime.h>
#include <hip/hip_bf16.h>
#include <hip/hip_fp16.h>

#define SEQ_T 100
#define HID 20
#define EMB_D 50
#define VOCAB_N 50000
#define TABW 60          // tab row stride (floats) = 60 gate cols [z20|r20|h20]
#define NTILE 3125       // VOCAB_N/16
#define BBLK 782         // build_table blocks (x4 waves = 3128 waves, 1 tile/wave)

typedef short sh8 __attribute__((ext_vector_type(8)));   // 8 bf16 bit patterns
typedef float f4  __attribute__((ext_vector_type(4)));

// ws layout (float/dword offsets). TOTAL footprint unchanged: 12,016,640 B.
#define OFF_U1P 0        // 600 dwords (60 cols x 10 packed f16 k-pairs)
#define OFF_W2P 600
#define OFF_U2P 1200
#define OFF_B1  3600     // 120 fp32
#define OFF_B2  3720     // 120 fp32
#define OFF_WD  3840     // 300 fp32
#define OFF_BD  4140     // 15 fp32
#define OFF_TAB 4160     // 50000*60 fp32

__device__ __forceinline__ float ldf(const void* p, int i, int isf) {
  return isf ? ((const float*)p)[i]
             : __bfloat162float(((const __hip_bfloat16*)p)[i]);
}
__device__ __forceinline__ short f2bf(float f) {   // RNE fp32->bf16 bits
  unsigned u = __float_as_uint(f);
  u += 0x7fffu + ((u >> 16) & 1u);
  return (short)(u >> 16);
}
__device__ __forceinline__ float rdl(float v, int l) {
  return __uint_as_float(__builtin_amdgcn_readlane(__float_as_uint(v), l));
}
__device__ __forceinline__ int detect_isf(const void* emb) {
  uint4 dv = ((const uint4*)emb)[threadIdx.x & 63];
  int big = 0;
#pragma unroll
  for (int i = 0; i < 4; ++i) {
    unsigned w = ((const unsigned*)&dv)[i];
    big |= (((w >> 7) & 0xFF) >= 140) | (((w >> 23) & 0xFF) >= 140);
  }
  return (__ballot(big) != 0ull) ? 1 : 0;
}

// tab = emb @ W1 + bi1 on the matrix cores (round-13 structure, verified).
__global__ __launch_bounds__(256) void build_table(
    const void* __restrict__ emb, const void* __restrict__ W1,
    const void* __restrict__ b1,
    const void* __restrict__ U1, const void* __restrict__ W2,
    const void* __restrict__ U2, const void* __restrict__ b2,
    const void* __restrict__ Wd, const void* __restrict__ bd,
    float* __restrict__ ws)
{
  const int isf = detect_isf(emb);
  if (blockIdx.x == 0) {                     // fold: weight prep
    const int t = threadIdx.x;
    unsigned* wsu = (unsigned*)ws;
    for (int i = t; i < 600; i += 256) {
      const int j = i / 10, p = i % 10;
      const int k0 = 2 * p, k1 = 2 * p + 1;
#define PK(M) ((unsigned)__half_as_ushort(__float2half_rn(ldf(M, k0 * 60 + j, isf))) | \
               ((unsigned)__half_as_ushort(__float2half_rn(ldf(M, k1 * 60 + j, isf))) << 16))
      wsu[OFF_U1P + i] = PK(U1);
      wsu[OFF_W2P + i] = PK(W2);
      wsu[OFF_U2P + i] = PK(U2);
#undef PK
    }
    for (int i = t; i < 120; i += 256) {
      ws[OFF_B1 + i] = ldf(b1, i, isf);
      ws[OFF_B2 + i] = ldf(b2, i, isf);
    }
    for (int i = t; i < 300; i += 256) ws[OFF_WD + i] = ldf(Wd, i, isf);
    for (int i = t; i < 15;  i += 256) ws[OFF_BD + i] = ldf(bd, i, isf);
  }

  const int L = threadIdx.x & 63, q = L >> 4, c = L & 15;
  const int wid = blockIdx.x * 4 + (threadIdx.x >> 6);
  float* __restrict__ tab = ws + OFF_TAB;

  __shared__ int4 sB[64][8];
  if (threadIdx.x < 64) {
#pragma unroll
    for (int nt = 0; nt < 4; ++nt) {
      const int col = nt * 16 + c;
      sh8 B0, B1;
#pragma unroll
      for (int jj = 0; jj < 8; ++jj) {
        const int k0 = q * 8 + jj, k1 = 32 + q * 8 + jj;
        B0[jj] = (col < TABW) ? f2bf(ldf(W1, k0 * TABW + col, isf)) : (short)0;
        B1[jj] = (col < TABW && k1 < EMB_D)
                     ? f2bf(ldf(W1, k1 * TABW + col, isf)) : (short)0;
      }
      sB[L][nt * 2]     = *(const int4*)&B0;
      sB[L][nt * 2 + 1] = *(const int4*)&B1;
    }
  }
  float bi[4];
#pragma unroll
  for (int nt = 0; nt < 4; ++nt) {
    const int col = nt * 16 + c;
    bi[nt] = (col < TABW) ? ldf(b1, col, isf) : 0.f;
  }
  __syncthreads();

  for (int tile = wid; tile < NTILE; tile += BBLK * 4) {
    const int v0 = tile * 16;
    sh8 A0, A1;
#pragma unroll
    for (int jj = 0; jj < 8; ++jj) { A0[jj] = 0; A1[jj] = 0; }
    if (!isf) {
      const unsigned short* eb = (const unsigned short*)emb;
      const size_t rb = (size_t)(v0 + c) * EMB_D;
#pragma unroll
      for (int i = 0; i < 4; ++i) {
        unsigned d = *(const unsigned*)(eb + rb + q * 8 + 2 * i);
        A0[2 * i] = (short)(d & 0xffff); A0[2 * i + 1] = (short)(d >> 16);
      }
      const int k1b = 32 + q * 8;
#pragma unroll
      for (int i = 0; i < 4; ++i) {
        const int k = k1b + 2 * i;
        if (k + 1 < EMB_D) {
          unsigned d = *(const unsigned*)(eb + rb + k);
          A1[2 * i] = (short)(d & 0xffff); A1[2 * i + 1] = (short)(d >> 16);
        }
      }
    } else {
      const float* ef = (const float*)emb;
      const size_t rb = (size_t)(v0 + c) * EMB_D;
#pragma unroll
      for (int jj = 0; jj < 8; ++jj) {
        const int k0 = q * 8 + jj, k1 = 32 + q * 8 + jj;
        A0[jj] = f2bf(ef[rb + k0]);
        A1[jj] = (k1 < EMB_D) ? f2bf(ef[rb + k1]) : (short)0;
      }
    }
#pragma unroll
    for (int nt = 0; nt < 4; ++nt) {
      int4 b0i = sB[L][nt * 2], b1i = sB[L][nt * 2 + 1];
      sh8 B0 = *(const sh8*)&b0i, B1 = *(const sh8*)&b1i;
      const int col = nt * 16 + c;
      f4 acc = { bi[nt], bi[nt], bi[nt], bi[nt] };
      acc = __builtin_amdgcn_mfma_f32_16x16x32_bf16(A0, B0, acc, 0, 0, 0);
      acc = __builtin_amdgcn_mfma_f32_16x16x32_bf16(A1, B1, acc, 0, 0, 0);
      if (col < TABW) {
#pragma unroll
        for (int r = 0; r < 4; ++r)
          tab[(size_t)(v0 + q * 4 + r) * TABW + col] = acc[r];
      }
    }
  }
}

// ONE batch element per wave; 100-step GRU in inline asm.
// ROUND-18: ZERO DS OPS IN THE LOOP. r15/16 (occupancy) null, r17 (layer
// pipelining) only -5% -> the binder is the per-CU DS pipe: 6 wave64
// bpermute/swizzle per element-step = 192 DS ops/CU/step, plus the
// lockstep lgkmcnt(0) stalls they force (per-SIMD VALU issue ~37%).
// New gate layout: z in lanes 0-19 (cols 0-19); r AND h both in lanes
// 32-51 (cols 20-39 on weight setA, cols 40-59 on weight setB). r->h
// move disappears (lane-local); hc->z is v_permlane32_swap (VALU,
// i<->i+32); pack-neighbor swizzle becomes DPP quad_perm. The permlane
// is made direction-proof (swap-operand ambiguity): non-source lanes
// forced to -4.0, duplicate, swap, v_max combine (real hc in [-1,1]).
// Cost: +30 dots/step, weight VGPRs 30->60 (~100 total, 4 waves/SIMD --
// fine, extra waves proved useless). Arithmetic bit-identical to r17.
__global__ __launch_bounds__(256, 4) void gru_main(
    const int* __restrict__ x, const float* __restrict__ ws,
    const void* __restrict__ emb, void* __restrict__ out)
{
  const int isf = detect_isf(emb);   // output dtype only
  const int j = threadIdx.x & 63;
  const int e = __builtin_amdgcn_readfirstlane(blockIdx.x * 4 + (threadIdx.x >> 6));

  // gate-column maps: setA: lane i<20 -> col i (z); lane 32+i -> col 20+i (r)
  //                   setB: lane 32+i -> col 40+i (h)
  const int jcA = (j < 20) ? j : (j >= 32 && j < 52) ? j - 12 : 0;
  const int jcB = (j >= 32 && j < 52) ? j + 8 : 40;

  const int* xr = x + (size_t)e * SEQ_T;
  const float* tab = ws + OFF_TAB;
  const int o1A = jcA * 40, o1B = jcB * 40;  // 10 packed dwords per column
  const int jcA4 = jcA * 4, jcB4 = jcB * 4;  // byte offsets in tab row
  const float brA1 = ws[OFF_B1 + 60 + jcA];
  const float brB1 = ws[OFF_B1 + 60 + jcB];
  const float biA2 = ws[OFF_B2 + jcA];
  const float biB2 = ws[OFF_B2 + jcB];
  const float brA2 = ws[OFF_B2 + 60 + jcA];
  const float brB2 = ws[OFF_B2 + 60 + jcB];
  float h2out;

  asm volatile(
    // ---- packed f16 weights. setA: U1 v10-19, W2 v20-29, U2 v30-39;
    //      setB: U1 v60-69, W2 v70-79, U2 v80-89 ----
    "global_load_dwordx4 v[10:13], %[o1A], %[wsp] offset:0\n\t"
    "global_load_dwordx4 v[14:17], %[o1A], %[wsp] offset:16\n\t"
    "global_load_dwordx2 v[18:19], %[o1A], %[wsp] offset:32\n\t"
    "v_add_u32 v44, 0x960, %[o1A]\n\t"
    "v_add_u32 v45, 0x12c0, %[o1A]\n\t"
    "global_load_dwordx4 v[20:23], v44, %[wsp] offset:0\n\t"
    "global_load_dwordx4 v[24:27], v44, %[wsp] offset:16\n\t"
    "global_load_dwordx2 v[28:29], v44, %[wsp] offset:32\n\t"
    "global_load_dwordx4 v[30:33], v45, %[wsp] offset:0\n\t"
    "global_load_dwordx4 v[34:37], v45, %[wsp] offset:16\n\t"
    "global_load_dwordx2 v[38:39], v45, %[wsp] offset:32\n\t"
    "global_load_dwordx4 v[60:63], %[o1B], %[wsp] offset:0\n\t"
    "global_load_dwordx4 v[64:67], %[o1B], %[wsp] offset:16\n\t"
    "global_load_dwordx2 v[68:69], %[o1B], %[wsp] offset:32\n\t"
    "v_add_u32 v46, 0x960, %[o1B]\n\t"
    "v_add_u32 v47, 0x12c0, %[o1B]\n\t"
    "global_load_dwordx4 v[70:73], v46, %[wsp] offset:0\n\t"
    "global_load_dwordx4 v[74:77], v46, %[wsp] offset:16\n\t"
    "global_load_dwordx2 v[78:79], v46, %[wsp] offset:32\n\t"
    "global_load_dwordx4 v[80:83], v47, %[wsp] offset:0\n\t"
    "global_load_dwordx4 v[84:87], v47, %[wsp] offset:16\n\t"
    "global_load_dwordx2 v[88:89], v47, %[wsp] offset:32\n\t"
    // ---- lane mask for real-hc lanes (32-51) ----
    "s_mov_b32 s60, 0\n\t"
    "s_mov_b32 s61, 0xfffff\n\t"
    // ---- h state zero: h1 s20-29/s40-49, h2 s30-39/s50-59 ----
    "s_mov_b64 s[20:21], 0\n\ts_mov_b64 s[22:23], 0\n\t"
    "s_mov_b64 s[24:25], 0\n\ts_mov_b64 s[26:27], 0\n\t"
    "s_mov_b64 s[28:29], 0\n\t"
    "s_mov_b64 s[30:31], 0\n\ts_mov_b64 s[32:33], 0\n\t"
    "s_mov_b64 s[34:35], 0\n\ts_mov_b64 s[36:37], 0\n\t"
    "s_mov_b64 s[38:39], 0\n\t"
    "s_mov_b64 s[40:41], 0\n\ts_mov_b64 s[42:43], 0\n\t"
    "s_mov_b64 s[44:45], 0\n\ts_mov_b64 s[46:47], 0\n\t"
    "s_mov_b64 s[48:49], 0\n\t"
    "s_mov_b64 s[50:51], 0\n\ts_mov_b64 s[52:53], 0\n\t"
    "s_mov_b64 s[54:55], 0\n\ts_mov_b64 s[56:57], 0\n\t"
    "s_mov_b64 s[58:59], 0\n\t"
    "v_mov_b32 v40, 0\n\t"
    "v_mov_b32 v41, 0\n\t"
    // ---- prime: mx0->(v53,v55), mx1->(v42,v56), mx2->(v43,v57) ----
    "s_load_dword s65, %[xp], 0x0\n\t"
    "s_load_dword s66, %[xp], 0x4\n\t"
    "s_load_dword s68, %[xp], 0x8\n\t"
    "s_waitcnt lgkmcnt(0)\n\t"
    "s_mul_i32 s65, s65, 240\n\t"
    "s_mul_i32 s66, s66, 240\n\t"
    "s_mul_i32 s68, s68, 240\n\t"
    "v_add_u32 v50, s65, %[jcA4]\n\t"
    "global_load_dword v53, v50, %[tabp]\n\t"
    "v_add_u32 v50, s65, %[jcB4]\n\t"
    "global_load_dword v55, v50, %[tabp]\n\t"
    "v_add_u32 v50, s66, %[jcA4]\n\t"
    "global_load_dword v42, v50, %[tabp]\n\t"
    "v_add_u32 v50, s66, %[jcB4]\n\t"
    "global_load_dword v56, v50, %[tabp]\n\t"
    "v_add_u32 v50, s68, %[jcA4]\n\t"
    "global_load_dword v43, v50, %[tabp]\n\t"
    "v_add_u32 v50, s68, %[jcB4]\n\t"
    "global_load_dword v57, v50, %[tabp]\n\t"
    "s_load_dword s65, %[xp], 0xc\n\t"     // idx3 (odd stream)
    "s_load_dword s68, %[xp], 0x10\n\t"    // idx4 (even stream)
    "s_movk_i32 s64, 0x14\n\t"             // next odd x-offset (idx5)
    "s_movk_i32 s69, 0x18\n\t"             // next even x-offset (idx6)
    "s_movk_i32 s67, 0x32\n\t"             // 50 unrolled iterations
    "s_waitcnt vmcnt(6)\n\t"               // weights ready
    // ======== PROLOGUE: L1(0)  (h1(-1)=s40-49 zeros, mx0=v53/v55) ========
    "v_mov_b32 v44, %[brA1]\n\t"
    "v_mov_b32 v58, %[brB1]\n\t"
    "v_dot2_f32_f16 v44, s40, v10, v44\n\t"
    "v_dot2_f32_f16 v58, s40, v60, v58\n\t"
    "v_dot2_f32_f16 v44, s41, v11, v44\n\t"
    "v_dot2_f32_f16 v58, s41, v61, v58\n\t"
    "v_dot2_f32_f16 v44, s42, v12, v44\n\t"
    "v_dot2_f32_f16 v58, s42, v62, v58\n\t"
    "v_dot2_f32_f16 v44, s43, v13, v44\n\t"
    "v_dot2_f32_f16 v58, s43, v63, v58\n\t"
    "v_dot2_f32_f16 v44, s44, v14, v44\n\t"
    "v_dot2_f32_f16 v58, s44, v64, v58\n\t"
    "v_dot2_f32_f16 v44, s45, v15, v44\n\t"
    "v_dot2_f32_f16 v58, s45, v65, v58\n\t"
    "v_dot2_f32_f16 v44, s46, v16, v44\n\t"
    "v_dot2_f32_f16 v58, s46, v66, v58\n\t"
    "v_dot2_f32_f16 v44, s47, v17, v44\n\t"
    "v_dot2_f32_f16 v58, s47, v67, v58\n\t"
    "v_dot2_f32_f16 v44, s48, v18, v44\n\t"
    "v_dot2_f32_f16 v58, s48, v68, v58\n\t"
    "v_dot2_f32_f16 v44, s49, v19, v44\n\t"
    "v_dot2_f32_f16 v58, s49, v69, v58\n\t"
    "s_waitcnt vmcnt(4)\n\t"               // mx0 pair ready
    "v_add_f32 v45, v53, v44\n\t"
    "v_mul_f32 v45, 0xbfb8aa3b, v45\n\t"
    "v_exp_f32 v45, v45\n\t"
    "s_nop 1\n\t"
    "v_add_f32 v45, 1.0, v45\n\t"
    "v_rcp_f32 v45, v45\n\t"
    "s_nop 1\n\t"
    "v_fma_f32 v47, v45, v58, v55\n\t"     // hp = r*accB + mxB
    "v_mul_f32 v47, 0x4038aa3b, v47\n\t"
    "v_exp_f32 v47, v47\n\t"
    "s_nop 1\n\t"
    "v_add_f32 v47, 1.0, v47\n\t"
    "v_rcp_f32 v47, v47\n\t"
    "s_nop 1\n\t"
    "v_fma_f32 v47, -2.0, v47, 1.0\n\t"    // hc
    "v_cndmask_b32 v47, -4.0, v47, s[60:61]\n\t"
    "v_mov_b32 v48, v47\n\t"
    "s_nop 1\n\t"
    "v_permlane32_swap_b32 v47, v48\n\t"
    "s_nop 1\n\t"
    "v_max_f32 v46, v47, v48\n\t"          // hc pulled to z-lanes
    "v_sub_f32 v48, v40, v46\n\t"
    "v_fma_f32 v40, v45, v48, v46\n\t"     // h1(0)
    "v_cvt_f16_f32 v46, v40\n\t"
    "s_nop 1\n\t"
    "v_mov_b32_dpp v48, v46 quad_perm:[1,0,3,2] row_mask:0xf bank_mask:0xf\n\t"
    "s_nop 1\n\t"
    "v_pack_b32_f16 v46, v46, v48\n\t"
    "s_nop 1\n\t"
    "v_readlane_b32 s20, v46, 0\n\t"
    "v_readlane_b32 s21, v46, 2\n\t"
    "v_readlane_b32 s22, v46, 4\n\t"
    "v_readlane_b32 s23, v46, 6\n\t"
    "v_readlane_b32 s24, v46, 8\n\t"
    "v_readlane_b32 s25, v46, 10\n\t"
    "v_readlane_b32 s26, v46, 12\n\t"
    "v_readlane_b32 s27, v46, 14\n\t"
    "v_readlane_b32 s28, v46, 16\n\t"
    "v_readlane_b32 s29, v46, 18\n\t"
    // ======== LOOP k=0..49 ========
    "0:\n\t"
    // ---- HALF A: L2(2k) || L1(2k+1). read {H1e s20-29, H2o s50-59},
    //      write {H2e s30-39, H1o s40-49}. mx = v42/v56.
    "v_mov_b32 v44, %[brA1]\n\t"
    "v_mov_b32 v58, %[brB1]\n\t"
    "v_mov_b32 v51, %[biA2]\n\t"
    "v_mov_b32 v54, %[biB2]\n\t"
    "v_mov_b32 v52, %[brA2]\n\t"
    "v_mov_b32 v55, %[brB2]\n\t"
    "v_dot2_f32_f16 v44, s20, v10, v44\n\t"
    "v_dot2_f32_f16 v51, s20, v20, v51\n\t"
    "v_dot2_f32_f16 v52, s50, v30, v52\n\t"
    "v_dot2_f32_f16 v58, s20, v60, v58\n\t"
    "v_dot2_f32_f16 v54, s20, v70, v54\n\t"
    "v_dot2_f32_f16 v55, s50, v80, v55\n\t"
    "v_dot2_f32_f16 v44, s21, v11, v44\n\t"
    "v_dot2_f32_f16 v51, s21, v21, v51\n\t"
    "v_dot2_f32_f16 v52, s51, v31, v52\n\t"
    "v_dot2_f32_f16 v58, s21, v61, v58\n\t"
    "v_dot2_f32_f16 v54, s21, v71, v54\n\t"
    "v_dot2_f32_f16 v55, s51, v81, v55\n\t"
    "v_dot2_f32_f16 v44, s22, v12, v44\n\t"
    "v_dot2_f32_f16 v51, s22, v22, v51\n\t"
    "v_dot2_f32_f16 v52, s52, v32, v52\n\t"
    "v_dot2_f32_f16 v58, s22, v62, v58\n\t"
    "v_dot2_f32_f16 v54, s22, v72, v54\n\t"
    "v_dot2_f32_f16 v55, s52, v82, v55\n\t"
    "v_dot2_f32_f16 v44, s23, v13, v44\n\t"
    "v_dot2_f32_f16 v51, s23, v23, v51\n\t"
    "v_dot2_f32_f16 v52, s53, v33, v52\n\t"
    "v_dot2_f32_f16 v58, s23, v63, v58\n\t"
    "v_dot2_f32_f16 v54, s23, v73, v54\n\t"
    "v_dot2_f32_f16 v55, s53, v83, v55\n\t"
    "v_dot2_f32_f16 v44, s24, v14, v44\n\t"
    "v_dot2_f32_f16 v51, s24, v24, v51\n\t"
    "v_dot2_f32_f16 v52, s54, v34, v52\n\t"
    "v_dot2_f32_f16 v58, s24, v64, v58\n\t"
    "v_dot2_f32_f16 v54, s24, v74, v54\n\t"
    "v_dot2_f32_f16 v55, s54, v84, v55\n\t"
    "v_dot2_f32_f16 v44, s25, v15, v44\n\t"
    "v_dot2_f32_f16 v51, s25, v25, v51\n\t"
    "v_dot2_f32_f16 v52, s55, v35, v52\n\t"
    "v_dot2_f32_f16 v58, s25, v65, v58\n\t"
    "v_dot2_f32_f16 v54, s25, v75, v54\n\t"
    "v_dot2_f32_f16 v55, s55, v85, v55\n\t"
    "v_dot2_f32_f16 v44, s26, v16, v44\n\t"
    "v_dot2_f32_f16 v51, s26, v26, v51\n\t"
    "v_dot2_f32_f16 v52, s56, v36, v52\n\t"
    "v_dot2_f32_f16 v58, s26, v66, v58\n\t"
    "v_dot2_f32_f16 v54, s26, v76, v54\n\t"
    "v_dot2_f32_f16 v55, s56, v86, v55\n\t"
    "v_dot2_f32_f16 v44, s27, v17, v44\n\t"
    "v_dot2_f32_f16 v51, s27, v27, v51\n\t"
    "v_dot2_f32_f16 v52, s57, v37, v52\n\t"
    "v_dot2_f32_f16 v58, s27, v67, v58\n\t"
    "v_dot2_f32_f16 v54, s27, v77, v54\n\t"
    "v_dot2_f32_f16 v55, s57, v87, v55\n\t"
    "v_dot2_f32_f16 v44, s28, v18, v44\n\t"
    "v_dot2_f32_f16 v51, s28, v28, v51\n\t"
    "v_dot2_f32_f16 v52, s58, v38, v52\n\t"
    "v_dot2_f32_f16 v58, s28, v68, v58\n\t"
    "v_dot2_f32_f16 v54, s28, v78, v54\n\t"
    "v_dot2_f32_f16 v55, s58, v88, v55\n\t"
    "v_dot2_f32_f16 v44, s29, v19, v44\n\t"
    "v_dot2_f32_f16 v51, s29, v29, v51\n\t"
    "v_dot2_f32_f16 v52, s59, v39, v52\n\t"
    "v_dot2_f32_f16 v58, s29, v69, v58\n\t"
    "v_dot2_f32_f16 v54, s29, v79, v54\n\t"
    "v_dot2_f32_f16 v55, s59, v89, v55\n\t"
    "s_waitcnt vmcnt(2)\n\t"               // mx(2k+1) in v42/v56
    "v_add_f32 v45, v42, v44\n\t"
    "v_add_f32 v53, v51, v52\n\t"
    "v_mul_f32 v45, 0xbfb8aa3b, v45\n\t"
    "v_mul_f32 v53, 0xbfb8aa3b, v53\n\t"
    "v_exp_f32 v45, v45\n\t"
    "v_exp_f32 v53, v53\n\t"
    "v_add_f32 v45, 1.0, v45\n\t"
    "v_add_f32 v53, 1.0, v53\n\t"
    "v_rcp_f32 v45, v45\n\t"
    "v_rcp_f32 v53, v53\n\t"
    "s_nop 0\n\t"
    "v_fma_f32 v47, v45, v58, v56\n\t"     // hp1 = r1*aB + mxB (v56 done)
    "v_fma_f32 v49, v53, v55, v54\n\t"     // hp2 = r2*n2B + m2B
    // ---- prefetch mx(2k+3), idx(2k+5) ----
    "s_waitcnt lgkmcnt(0)\n\t"
    "s_mul_i32 s66, s65, 240\n\t"
    "v_add_u32 v50, s66, %[jcA4]\n\t"
    "global_load_dword v42, v50, %[tabp]\n\t"
    "v_add_u32 v50, s66, %[jcB4]\n\t"
    "global_load_dword v56, v50, %[tabp]\n\t"
    "s_min_u32 s64, s64, 396\n\t"
    "s_load_dword s65, %[xp], s64\n\t"
    "s_add_u32 s64, s64, 8\n\t"
    // ---- tanh chain ----
    "v_mul_f32 v47, 0x4038aa3b, v47\n\t"
    "v_mul_f32 v49, 0x4038aa3b, v49\n\t"
    "v_exp_f32 v47, v47\n\t"
    "v_exp_f32 v49, v49\n\t"
    "v_add_f32 v47, 1.0, v47\n\t"
    "v_add_f32 v49, 1.0, v49\n\t"
    "v_rcp_f32 v47, v47\n\t"
    "v_rcp_f32 v49, v49\n\t"
    "s_nop 0\n\t"
    "v_fma_f32 v47, -2.0, v47, 1.0\n\t"    // hc1
    "v_fma_f32 v49, -2.0, v49, 1.0\n\t"    // hc2
    "v_cndmask_b32 v47, -4.0, v47, s[60:61]\n\t"
    "v_cndmask_b32 v49, -4.0, v49, s[60:61]\n\t"
    "v_mov_b32 v48, v47\n\t"
    "v_mov_b32 v59, v49\n\t"
    "s_nop 1\n\t"
    "v_permlane32_swap_b32 v47, v48\n\t"
    "v_permlane32_swap_b32 v49, v59\n\t"
    "s_nop 1\n\t"
    "v_max_f32 v46, v47, v48\n\t"          // hc1 -> z-lanes
    "v_max_f32 v59, v49, v59\n\t"          // hc2 -> z-lanes
    "v_sub_f32 v48, v40, v46\n\t"
    "v_fma_f32 v40, v45, v48, v46\n\t"     // h1(2k+1)
    "v_sub_f32 v48, v41, v59\n\t"
    "v_fma_f32 v41, v53, v48, v59\n\t"     // h2(2k)
    "v_cvt_f16_f32 v46, v40\n\t"
    "v_cvt_f16_f32 v47, v41\n\t"
    "s_nop 1\n\t"
    "v_mov_b32_dpp v48, v46 quad_perm:[1,0,3,2] row_mask:0xf bank_mask:0xf\n\t"
    "v_mov_b32_dpp v49, v47 quad_perm:[1,0,3,2] row_mask:0xf bank_mask:0xf\n\t"
    "s_nop 1\n\t"
    "v_pack_b32_f16 v46, v46, v48\n\t"
    "v_pack_b32_f16 v47, v47, v49\n\t"
    "s_nop 1\n\t"
    "v_readlane_b32 s40, v46, 0\n\t"
    "v_readlane_b32 s41, v46, 2\n\t"
    "v_readlane_b32 s42, v46, 4\n\t"
    "v_readlane_b32 s43, v46, 6\n\t"
    "v_readlane_b32 s44, v46, 8\n\t"
    "v_readlane_b32 s45, v46, 10\n\t"
    "v_readlane_b32 s46, v46, 12\n\t"
    "v_readlane_b32 s47, v46, 14\n\t"
    "v_readlane_b32 s48, v46, 16\n\t"
    "v_readlane_b32 s49, v46, 18\n\t"
    "v_readlane_b32 s30, v47, 0\n\t"
    "v_readlane_b32 s31, v47, 2\n\t"
    "v_readlane_b32 s32, v47, 4\n\t"
    "v_readlane_b32 s33, v47, 6\n\t"
    "v_readlane_b32 s34, v47, 8\n\t"
    "v_readlane_b32 s35, v47, 10\n\t"
    "v_readlane_b32 s36, v47, 12\n\t"
    "v_readlane_b32 s37, v47, 14\n\t"
    "v_readlane_b32 s38, v47, 16\n\t"
    "v_readlane_b32 s39, v47, 18\n\t"
    // ---- HALF B: L2(2k+1) || L1(2k+2). read {H1o s40-49, H2e s30-39},
    //      write {H2o s50-59, H1e s20-29}. mx = v43/v57.
    "v_mov_b32 v44, %[brA1]\n\t"
    "v_mov_b32 v58, %[brB1]\n\t"
    "v_mov_b32 v51, %[biA2]\n\t"
    "v_mov_b32 v54, %[biB2]\n\t"
    "v_mov_b32 v52, %[brA2]\n\t"
    "v_mov_b32 v55, %[brB2]\n\t"
    "v_dot2_f32_f16 v44, s40, v10, v44\n\t"
    "v_dot2_f32_f16 v51, s40, v20, v51\n\t"
    "v_dot2_f32_f16 v52, s30, v30, v52\n\t"
    "v_dot2_f32_f16 v58, s40, v60, v58\n\t"
    "v_dot2_f32_f16 v54, s40, v70, v54\n\t"
    "v_dot2_f32_f16 v55, s30, v80, v55\n\t"
    "v_dot2_f32_f16 v44, s41, v11, v44\n\t"
    "v_dot2_f32_f16 v51, s41, v21, v51\n\t"
    "v_dot2_f32_f16 v52, s31, v31, v52\n\t"
    "v_dot2_f32_f16 v58, s41, v61, v58\n\t"
    "v_dot2_f32_f16 v54, s41, v71, v54\n\t"
    "v_dot2_f32_f16 v55, s31, v81, v55\n\t"
    "v_dot2_f32_f16 v44, s42, v12, v44\n\t"
    "v_dot2_f32_f16 v51, s42, v22, v51\n\t"
    "v_dot2_f32_f16 v52, s32, v32, v52\n\t"
    "v_dot2_f32_f16 v58, s42, v62, v58\n\t"
    "v_dot2_f32_f16 v54, s42, v72, v54\n\t"
    "v_dot2_f32_f16 v55, s32, v82, v55\n\t"
    "v_dot2_f32_f16 v44, s43, v13, v44\n\t"
    "v_dot2_f32_f16 v51, s43, v23, v51\n\t"
    "v_dot2_f32_f16 v52, s33, v33, v52\n\t"
    "v_dot2_f32_f16 v58, s43, v63, v58\n\t"
    "v_dot2_f32_f16 v54, s43, v73, v54\n\t"
    "v_dot2_f32_f16 v55, s33, v83, v55\n\t"
    "v_dot2_f32_f16 v44, s44, v14, v44\n\t"
    "v_dot2_f32_f16 v51, s44, v24, v51\n\t"
    "v_dot2_f32_f16 v52, s34, v34, v52\n\t"
    "v_dot2_f32_f16 v58, s44, v64, v58\n\t"
    "v_dot2_f32_f16 v54, s44, v74, v54\n\t"
    "v_dot2_f32_f16 v55, s34, v84, v55\n\t"
    "v_dot2_f32_f16 v44, s45, v15, v44\n\t"
    "v_dot2_f32_f16 v51, s45, v25, v51\n\t"
    "v_dot2_f32_f16 v52, s35, v35, v52\n\t"
    "v_dot2_f32_f16 v58, s45, v65, v58\n\t"
    "v_dot2_f32_f16 v54, s45, v75, v54\n\t"
    "v_dot2_f32_f16 v55, s35, v85, v55\n\t"
    "v_dot2_f32_f16 v44, s46, v16, v44\n\t"
    "v_dot2_f32_f16 v51, s46, v26, v51\n\t"
    "v_dot2_f32_f16 v52, s36, v36, v52\n\t"
    "v_dot2_f32_f16 v58, s46, v66, v58\n\t"
    "v_dot2_f32_f16 v54, s46, v76, v54\n\t"
    "v_dot2_f32_f16 v55, s36, v86, v55\n\t"
    "v_dot2_f32_f16 v44, s47, v17, v44\n\t"
    "v_dot2_f32_f16 v51, s47, v27, v51\n\t"
    "v_dot2_f32_f16 v52, s37, v37, v52\n\t"
    "v_dot2_f32_f16 v58, s47, v67, v58\n\t"
    "v_dot2_f32_f16 v54, s47, v77, v54\n\t"
    "v_dot2_f32_f16 v55, s37, v87, v55\n\t"
    "v_dot2_f32_f16 v44, s48, v18, v44\n\t"
    "v_dot2_f32_f16 v51, s48, v28, v51\n\t"
    "v_dot2_f32_f16 v52, s38, v38, v52\n\t"
    "v_dot2_f32_f16 v58, s48, v68, v58\n\t"
    "v_dot2_f32_f16 v54, s48, v78, v54\n\t"
    "v_dot2_f32_f16 v55, s38, v88, v55\n\t"
    "v_dot2_f32_f16 v44, s49, v19, v44\n\t"
    "v_dot2_f32_f16 v51, s49, v29, v51\n\t"
    "v_dot2_f32_f16 v52, s39, v39, v52\n\t"
    "v_dot2_f32_f16 v58, s49, v69, v58\n\t"
    "v_dot2_f32_f16 v54, s49, v79, v54\n\t"
    "v_dot2_f32_f16 v55, s39, v89, v55\n\t"
    "s_waitcnt vmcnt(2)\n\t"               // mx(2k+2) in v43/v57
    "v_add_f32 v45, v43, v44\n\t"
    "v_add_f32 v53, v51, v52\n\t"
    "v_mul_f32 v45, 0xbfb8aa3b, v45\n\t"
    "v_mul_f32 v53, 0xbfb8aa3b, v53\n\t"
    "v_exp_f32 v45, v45\n\t"
    "v_exp_f32 v53, v53\n\t"
    "v_add_f32 v45, 1.0, v45\n\t"
    "v_add_f32 v53, 1.0, v53\n\t"
    "v_rcp_f32 v45, v45\n\t"
    "v_rcp_f32 v53, v53\n\t"
    "s_nop 0\n\t"
    "v_fma_f32 v47, v45, v58, v57\n\t"     // hp1 (v57 done)
    "v_fma_f32 v49, v53, v55, v54\n\t"     // hp2
    // ---- prefetch mx(2k+4), idx(2k+6) ----
    "s_waitcnt lgkmcnt(0)\n\t"
    "s_mul_i32 s66, s68, 240\n\t"
    "v_add_u32 v50, s66, %[jcA4]\n\t"
    "global_load_dword v43, v50, %[tabp]\n\t"
    "v_add_u32 v50, s66, %[jcB4]\n\t"
    "global_load_dword v57, v50, %[tabp]\n\t"
    "s_min_u32 s69, s69, 392\n\t"
    "s_load_dword s68, %[xp], s69\n\t"
    "s_add_u32 s69, s69, 8\n\t"
    // ---- tanh chain ----
    "v_mul_f32 v47, 0x4038aa3b, v47\n\t"
    "v_mul_f32 v49, 0x4038aa3b, v49\n\t"
    "v_exp_f32 v47, v47\n\t"
    "v_exp_f32 v49, v49\n\t"
    "v_add_f32 v47, 1.0, v47\n\t"
    "v_add_f32 v49, 1.0, v49\n\t"
    "v_rcp_f32 v47, v47\n\t"
    "v_rcp_f32 v49, v49\n\t"
    "s_nop 0\n\t"
    "v_fma_f32 v47, -2.0, v47, 1.0\n\t"
    "v_fma_f32 v49, -2.0, v49, 1.0\n\t"
    "v_cndmask_b32 v47, -4.0, v47, s[60:61]\n\t"
    "v_cndmask_b32 v49, -4.0, v49, s[60:61]\n\t"
    "v_mov_b32 v48, v47\n\t"
    "v_mov_b32 v59, v49\n\t"
    "s_nop 1\n\t"
    "v_permlane32_swap_b32 v47, v48\n\t"
    "v_permlane32_swap_b32 v49, v59\n\t"
    "s_nop 1\n\t"
    "v_max_f32 v46, v47, v48\n\t"
    "v_max_f32 v59, v49, v59\n\t"
    "v_sub_f32 v48, v40, v46\n\t"
    "v_fma_f32 v40, v45, v48, v46\n\t"     // h1(2k+2)
    "v_sub_f32 v48, v41, v59\n\t"
    "v_fma_f32 v41, v53, v48, v59\n\t"     // h2(2k+1)
    "v_cvt_f16_f32 v46, v40\n\t"
    "v_cvt_f16_f32 v47, v41\n\t"
    "s_nop 1\n\t"
    "v_mov_b32_dpp v48, v46 quad_perm:[1,0,3,2] row_mask:0xf bank_mask:0xf\n\t"
    "v_mov_b32_dpp v49, v47 quad_perm:[1,0,3,2] row_mask:0xf bank_mask:0xf\n\t"
    "s_nop 1\n\t"
    "v_pack_b32_f16 v46, v46, v48\n\t"
    "v_pack_b32_f16 v47, v47, v49\n\t"
    "s_nop 1\n\t"
    "v_readlane_b32 s20, v46, 0\n\t"
    "v_readlane_b32 s21, v46, 2\n\t"
    "v_readlane_b32 s22, v46, 4\n\t"
    "v_readlane_b32 s23, v46, 6\n\t"
    "v_readlane_b32 s24, v46, 8\n\t"
    "v_readlane_b32 s25, v46, 10\n\t"
    "v_readlane_b32 s26, v46, 12\n\t"
    "v_readlane_b32 s27, v46, 14\n\t"
    "v_readlane_b32 s28, v46, 16\n\t"
    "v_readlane_b32 s29, v46, 18\n\t"
    "v_readlane_b32 s50, v47, 0\n\t"
    "v_readlane_b32 s51, v47, 2\n\t"
    "v_readlane_b32 s52, v47, 4\n\t"
    "v_readlane_b32 s53, v47, 6\n\t"
    "v_readlane_b32 s54, v47, 8\n\t"
    "v_readlane_b32 s55, v47, 10\n\t"
    "v_readlane_b32 s56, v47, 12\n\t"
    "v_readlane_b32 s57, v47, 14\n\t"
    "v_readlane_b32 s58, v47, 16\n\t"
    "v_readlane_b32 s59, v47, 18\n\t"
    "s_sub_u32 s67, s67, 1\n\t"
    "s_cmp_lg_u32 s67, 0\n\t"
    "s_cbranch_scc1 0b\n\t"
    "s_waitcnt vmcnt(0) lgkmcnt(0)\n\t"
    "v_mov_b32 %[h2o], v41\n\t"
    : [h2o] "=v"(h2out)
    : [wsp] "s"(ws), [xp] "s"(xr), [tabp] "s"(tab),
      [o1A] "v"(o1A), [o1B] "v"(o1B), [jcA4] "v"(jcA4), [jcB4] "v"(jcB4),
      [brA1] "v"(brA1), [brB1] "v"(brB1), [biA2] "v"(biA2),
      [biB2] "v"(biB2), [brA2] "v"(brA2), [brB2] "v"(brB2)
    : "memory", "vcc", "scc",
      "v10","v11","v12","v13","v14","v15","v16","v17","v18","v19",
      "v20","v21","v22","v23","v24","v25","v26","v27","v28","v29",
      "v30","v31","v32","v33","v34","v35","v36","v37","v38","v39",
      "v40","v41","v42","v43","v44","v45","v46","v47","v48","v49","v50",
      "v51","v52","v53","v54","v55","v56","v57","v58","v59",
      "v60","v61","v62","v63","v64","v65","v66","v67","v68","v69",
      "v70","v71","v72","v73","v74","v75","v76","v77","v78","v79",
      "v80","v81","v82","v83","v84","v85","v86","v87","v88","v89",
      "s20","s21","s22","s23","s24","s25","s26","s27","s28","s29",
      "s30","s31","s32","s33","s34","s35","s36","s37","s38","s39",
      "s40","s41","s42","s43","s44","s45","s46","s47","s48","s49",
      "s50","s51","s52","s53","s54","s55","s56","s57","s58","s59",
      "s60","s61","s64","s65","s66","s67","s68","s69");

  // ---- dense: logits = h2 @ Wd + bd (h2 master fp32 in h2out lanes 0..19) ----
  if (j < 15) {
    float a = ws[OFF_BD + j];
#pragma unroll
    for (int k = 0; k < HID; ++k)
      a = fmaf(rdl(h2out, k), ws[OFF_WD + k * 15 + j], a);
    if (isf) ((float*)out)[(size_t)e * 15 + j] = a;
    else ((__hip_bfloat16*)out)[(size_t)e * 15 + j] = __float2bfloat16(a);
  }
}

extern "C" void kernel_launch(void* const* d_in, const int* in_sizes, int n_in,
                              void* d_out, int out_size, void* d_ws, size_t ws_size,
                              hipStream_t stream) {
  const int* x    = (const int*)d_in[0];
  const void* emb = d_in[1];
  const void* W1  = d_in[2];
  const void* U1  = d_in[3];
  const void* b1  = d_in[4];
  const void* W2  = d_in[5];
  const void* U2  = d_in[6];
  const void* b2  = d_in[7];
  const void* Wd  = d_in[8];
  const void* bd  = d_in[9];
  float* ws = (float*)d_ws;   // 12,016,640 B used (proven safe)

  build_table<<<BBLK, 256, 0, stream>>>(
      emb, W1, b1, U1, W2, U2, b2, Wd, bd, ws);
  gru_main<<<2048, 256, 0, stream>>>(x, ws, emb, d_out);
}

// Round 5
// 271.986 us; speedup vs baseline: 1.0665x; 1.0665x over previous
//
#include <hip/hip_runtime.h>
#include <hip/hip_bf16.h>
#include <hip/hip_fp16.h>

#define SEQ_T 100
#define VOCAB_N 50000

typedef short    sh8 __attribute__((ext_vector_type(8)));   // 8 bf16 bits
typedef _Float16 hf8 __attribute__((ext_vector_type(8)));   // 8 f16
typedef float    f4  __attribute__((ext_vector_type(4)));

// ws layout (dword offsets), total 1,608,271 dwords = 6.44 MB (< 12MB proven)
// B-frags: 30 frags x 1KB. Order: W1kt0 nt0-5 | W1kt1 nt0-5 (bf16) |
//          U1 nt0-5 | W2 nt0-5 | U2 nt0-5 (f16).
// Gate-padded N=96: z cols 0-31 (20 real), r 32-63, h 64-95 -> z,r,h for a
// given (elem,col) sit in the SAME lane of the MFMA D layout.
#define OFF_BF   0
#define OFF_BIAS 7680     // bzr1[64] bxh1[32] brh1[32] bzr2[64] bxh2[32] brh2[32]
#define OFF_WD   7936     // 300
#define OFF_BD   8236     // 15
#define OFF_TABA 8256     // 50000 x 32 dwords: emb rows as bf16 padded to 64 cols

__device__ __forceinline__ float ldf(const void* p, int i, int isf) {
  return isf ? ((const float*)p)[i]
             : __bfloat162float(((const __hip_bfloat16*)p)[i]);
}
__device__ __forceinline__ unsigned short f2bf(float f) {   // RNE fp32->bf16
  unsigned u = __float_as_uint(f);
  u += 0x7fffu + ((u >> 16) & 1u);
  return (unsigned short)(u >> 16);
}
__device__ __forceinline__ int detect_isf(const void* emb) {
  uint4 dv = ((const uint4*)emb)[threadIdx.x & 63];
  int big = 0;
#pragma unroll
  for (int i = 0; i < 4; ++i) {
    unsigned w = ((const unsigned*)&dv)[i];
    big |= (((w >> 7) & 0xFF) >= 140) | (((w >> 23) & 0xFF) >= 140);
  }
  return (__ballot(big) != 0ull) ? 1 : 0;
}
// exact r17 gate primitives (v_exp_f32 = 2^x, v_rcp): sequences bit-match
__device__ __forceinline__ float vexp2(float x) {
  float r; asm("v_exp_f32 %0, %1\n\ts_nop 1" : "=v"(r) : "v"(x)); return r;
}
__device__ __forceinline__ float vrcp(float x) {
  float r; asm("v_rcp_f32 %0, %1\n\ts_nop 1" : "=v"(r) : "v"(x)); return r;
}
__device__ __forceinline__ unsigned short cvw(const void* M, int idx, int isf, int fp16) {
  float f = ldf(M, idx, isf);
  return fp16 ? __half_as_ushort(__float2half_rn(f)) : f2bf(f);
}

// Prep: B-frags (gate-padded, MFMA B layout: lane&15=col-n, k=(lane>>4)*8+jj),
// biases (zr gets bi+br since z,r args are mx+mh sums; xh gets bi_h, rh br_h),
// Wd/bd, and tabA = emb as bf16 padded to 64 cols (A-operand-ready rows).
__global__ __launch_bounds__(256) void build_pre(
    const void* __restrict__ emb, const void* __restrict__ W1,
    const void* __restrict__ b1,
    const void* __restrict__ U1, const void* __restrict__ W2,
    const void* __restrict__ U2, const void* __restrict__ b2,
    const void* __restrict__ Wd, const void* __restrict__ bd,
    float* __restrict__ ws)
{
  const int isf = detect_isf(emb);
  unsigned* wsu = (unsigned*)ws;
  if (blockIdx.x == 0) {
    for (int i = threadIdx.x; i < 7680; i += 256) {
      const int f = i >> 8, L = (i >> 2) & 63, dw = i & 3;
      const void* M; int kt, nt, kmax, fp16;
      if (f < 6)       { M = W1; kt = 0; nt = f;      kmax = 50; fp16 = 0; }
      else if (f < 12) { M = W1; kt = 1; nt = f - 6;  kmax = 50; fp16 = 0; }
      else if (f < 18) { M = U1; kt = 0; nt = f - 12; kmax = 20; fp16 = 1; }
      else if (f < 24) { M = W2; kt = 0; nt = f - 18; kmax = 20; fp16 = 1; }
      else             { M = U2; kt = 0; nt = f - 24; kmax = 20; fp16 = 1; }
      const int n = nt * 16 + (L & 15);
      const int gc = n < 32 ? n : (n < 64 ? n - 12 : n - 24); // z / r(+20) / h(+40)
      const int gcv = (n & 31) < 20;
      const int k0 = kt * 32 + ((L >> 4) * 8) + dw * 2;
      unsigned lo = 0, hi = 0;
      if (gcv && k0 < kmax)     lo = cvw(M, k0 * 60 + gc, isf, fp16);
      if (gcv && k0 + 1 < kmax) hi = cvw(M, (k0 + 1) * 60 + gc, isf, fp16);
      wsu[OFF_BF + i] = lo | (hi << 16);
    }
    {
      int i = threadIdx.x;                       // 256 bias values, 256 thr
      const int half = i >> 7;
      const void* B = half ? b2 : b1;
      const int n = i & 127;
      float v = 0.f;
      if (n < 64)      { int gc = n < 32 ? n : n - 12;
                         if ((n & 31) < 20) v = ldf(B, gc, isf) + ldf(B, 60 + gc, isf); }
      else if (n < 96) { int cc = n - 64; if (cc < 20) v = ldf(B, 40 + cc, isf); }
      else             { int cc = n - 96; if (cc < 20) v = ldf(B, 100 + cc, isf); }
      ws[OFF_BIAS + i] = v;
    }
    for (int i = threadIdx.x; i < 300; i += 256) ws[OFF_WD + i] = ldf(Wd, i, isf);
    for (int i = threadIdx.x; i < 15;  i += 256) ws[OFF_BD + i] = ldf(bd, i, isf);
  }
  // tabA: 1.6M dwords, coalesced grid-stride. Row = 128B: 25 data dwords + 7 zero.
  const int total = VOCAB_N * 32;
  for (int d = blockIdx.x * 256 + threadIdx.x; d < total; d += 256 * 256) {
    const int row = d >> 5, c2 = d & 31;
    unsigned v = 0;
    if (c2 < 25) {
      if (!isf) v = ((const unsigned*)emb)[row * 25 + c2];
      else {
        const float* ef = (const float*)emb;
        v = (unsigned)f2bf(ef[row * 50 + 2 * c2]) |
            ((unsigned)f2bf(ef[row * 50 + 2 * c2 + 1]) << 16);
      }
    }
    wsu[OFF_TABA + d] = v;
  }
}

// ROUND-19: 8 batch elements PER WAVE, matvecs on matrix cores.
// Evidence r14-r18: wall tracks VALU-instr/step/SIMD with ~4.3x overhead;
// occupancy null, chain-shortening null, DS-removal regressed via +instr.
// => reduce instructions per ELEMENT. MFMA D layout (verified in the old
// build_table): row=(lane>>4)*4+reg, col=lane&15. A: row=lane&15, k=(lane>>4)*8+jj.
// Gate-padded cols put z/r/h of one (elem,col) in one lane: gates lane-local.
// h state kept BOTH as D-layout f32 (for z*h term) and as f16 A-frag via a
// wave-private LDS transpose (f16 h == r17's representation -> same numerics).
__global__ __launch_bounds__(64) void gru_main(
    const int* __restrict__ x, const float* __restrict__ ws,
    const void* __restrict__ emb, void* __restrict__ out)
{
  const int isf = detect_isf(emb);            // output dtype only
  const int l = threadIdx.x, c = l & 15, q = l >> 4;
  const int wid = blockIdx.x;

  __shared__ _Float16 hb1[16][40];            // [elem][k] rows padded to 80B
  __shared__ _Float16 hb2[16][40];            // (80B: 16B-aligned, 2-way banks)
  __shared__ float    fb[16][21];
  for (int i = l; i < 640; i += 64) {
    ((_Float16*)hb1)[i] = (_Float16)0.f;
    ((_Float16*)hb2)[i] = (_Float16)0.f;
  }
  asm volatile("s_waitcnt lgkmcnt(0)" ::: "memory");

  const uint4* wsu4 = (const uint4*)ws;
  sh8 w1f[12]; hf8 u1f[6], w2f[6], u2f[6];
#pragma unroll
  for (int f = 0; f < 12; ++f) { uint4 u = wsu4[f * 64 + l];        w1f[f] = *(sh8*)&u; }
#pragma unroll
  for (int f = 0; f < 6; ++f)  { uint4 u = wsu4[(12 + f) * 64 + l]; u1f[f] = *(hf8*)&u; }
#pragma unroll
  for (int f = 0; f < 6; ++f)  { uint4 u = wsu4[(18 + f) * 64 + l]; w2f[f] = *(hf8*)&u; }
#pragma unroll
  for (int f = 0; f < 6; ++f)  { uint4 u = wsu4[(24 + f) * 64 + l]; u2f[f] = *(hf8*)&u; }

  float bzr1[4], bzr2[4], bxh1[2], brh1[2], bxh2[2], brh2[2];
#pragma unroll
  for (int nt = 0; nt < 4; ++nt) {
    bzr1[nt] = ws[OFF_BIAS + nt * 16 + c];
    bzr2[nt] = ws[OFF_BIAS + 128 + nt * 16 + c];
  }
#pragma unroll
  for (int i = 0; i < 2; ++i) {
    bxh1[i] = ws[OFF_BIAS + 64 + i * 16 + c];
    brh1[i] = ws[OFF_BIAS + 96 + i * 16 + c];
    bxh2[i] = ws[OFF_BIAS + 192 + i * 16 + c];
    brh2[i] = ws[OFF_BIAS + 224 + i * 16 + c];
  }

  const uint4* ta = (const uint4*)(ws + OFF_TABA);
  const int* xb = x + (size_t)(wid * 8 + (c & 7)) * SEQ_T;  // A rows 8-15 dup 0-7
  int xn = xb[0];
  int x2 = xb[1];
  uint4 ea0 = ta[xn * 8 + q], ea1 = ta[xn * 8 + 4 + q];     // emb A-frags (t=0)
  xn = x2; x2 = xb[2];

  f4 h1t[2] = {{0.f,0.f,0.f,0.f},{0.f,0.f,0.f,0.f}};
  f4 h2t[2] = {{0.f,0.f,0.f,0.f},{0.f,0.f,0.f,0.f}};
  hf8 h1a = {(_Float16)0.f};
  hf8 h2a = {(_Float16)0.f};

  for (int t = 0; t < SEQ_T; ++t) {
    // prefetch emb frags for t+1 and x for t+2 (used a full iteration later)
    uint4 na0 = ta[xn * 8 + q], na1 = ta[xn * 8 + 4 + q];
    const int tpp = (t + 3 < SEQ_T) ? t + 3 : SEQ_T - 1;
    const int xnn = xb[tpp];
    const sh8 eA = *(const sh8*)&ea0, eB = *(const sh8*)&ea1;

    // ---- layer 1 MFMAs: zr = (bi+br) + E@W1 + h1@U1 ; xh = bi_h + E@W1_h ;
    //      rh = br_h + h1@U1_h ----
    f4 azr[4], axh[2], arh[2];
#pragma unroll
    for (int nt = 0; nt < 4; ++nt) {
      f4 a = { bzr1[nt], bzr1[nt], bzr1[nt], bzr1[nt] };
      a = __builtin_amdgcn_mfma_f32_16x16x32_bf16(eA, w1f[nt], a, 0, 0, 0);
      a = __builtin_amdgcn_mfma_f32_16x16x32_bf16(eB, w1f[6 + nt], a, 0, 0, 0);
      a = __builtin_amdgcn_mfma_f32_16x16x32_f16(h1a, u1f[nt], a, 0, 0, 0);
      azr[nt] = a;
    }
#pragma unroll
    for (int i = 0; i < 2; ++i) {
      f4 a = { bxh1[i], bxh1[i], bxh1[i], bxh1[i] };
      a = __builtin_amdgcn_mfma_f32_16x16x32_bf16(eA, w1f[4 + i], a, 0, 0, 0);
      a = __builtin_amdgcn_mfma_f32_16x16x32_bf16(eB, w1f[10 + i], a, 0, 0, 0);
      axh[i] = a;
      f4 b = { brh1[i], brh1[i], brh1[i], brh1[i] };
      b = __builtin_amdgcn_mfma_f32_16x16x32_f16(h1a, u1f[4 + i], b, 0, 0, 0);
      arh[i] = b;
    }
    // ---- gates layer 1 (lane-local; exact r17 sequences) ----
#pragma unroll
    for (int i = 0; i < 2; ++i)
#pragma unroll
      for (int r = 0; r < 4; ++r) {
        float z  = vrcp(1.f + vexp2(azr[i][r] * -1.44269504f));
        float rg = vrcp(1.f + vexp2(azr[2 + i][r] * -1.44269504f));
        float hp = fmaf(rg, arh[i][r], axh[i][r]);
        float hc = fmaf(-2.f, vrcp(1.f + vexp2(hp * 2.88539008f)), 1.f);
        float hn = fmaf(z, h1t[i][r] - hc, hc);
        h1t[i][r] = hn;
        if (c + 16 * i < 20) hb1[q * 4 + r][c + 16 * i] = (_Float16)hn;
      }
    asm volatile("s_waitcnt lgkmcnt(0)" ::: "memory");
    h1a = *(const hf8*)&hb1[c][q * 8];

    // ---- layer 2 MFMAs: zr = (bi2+br2) + h1new@W2 + h2@U2 ; xh = bi2_h +
    //      h1new@W2_h ; rh = br2_h + h2@U2_h ----
#pragma unroll
    for (int nt = 0; nt < 4; ++nt) {
      f4 a = { bzr2[nt], bzr2[nt], bzr2[nt], bzr2[nt] };
      a = __builtin_amdgcn_mfma_f32_16x16x32_f16(h1a, w2f[nt], a, 0, 0, 0);
      a = __builtin_amdgcn_mfma_f32_16x16x32_f16(h2a, u2f[nt], a, 0, 0, 0);
      azr[nt] = a;
    }
#pragma unroll
    for (int i = 0; i < 2; ++i) {
      f4 a = { bxh2[i], bxh2[i], bxh2[i], bxh2[i] };
      a = __builtin_amdgcn_mfma_f32_16x16x32_f16(h1a, w2f[4 + i], a, 0, 0, 0);
      axh[i] = a;
      f4 b = { brh2[i], brh2[i], brh2[i], brh2[i] };
      b = __builtin_amdgcn_mfma_f32_16x16x32_f16(h2a, u2f[4 + i], b, 0, 0, 0);
      arh[i] = b;
    }
#pragma unroll
    for (int i = 0; i < 2; ++i)
#pragma unroll
      for (int r = 0; r < 4; ++r) {
        float z  = vrcp(1.f + vexp2(azr[i][r] * -1.44269504f));
        float rg = vrcp(1.f + vexp2(azr[2 + i][r] * -1.44269504f));
        float hp = fmaf(rg, arh[i][r], axh[i][r]);
        float hc = fmaf(-2.f, vrcp(1.f + vexp2(hp * 2.88539008f)), 1.f);
        float hn = fmaf(z, h2t[i][r] - hc, hc);
        h2t[i][r] = hn;
        if (c + 16 * i < 20) hb2[q * 4 + r][c + 16 * i] = (_Float16)hn;
      }
    asm volatile("s_waitcnt lgkmcnt(0)" ::: "memory");
    h2a = *(const hf8*)&hb2[c][q * 8];

    ea0 = na0; ea1 = na1; xn = x2; x2 = xnn;   // rotate prefetch pipeline
  }

  // ---- epilogue: logits = h2 @ Wd + bd via LDS transpose of h2t ----
#pragma unroll
  for (int i = 0; i < 2; ++i)
#pragma unroll
    for (int r = 0; r < 4; ++r)
      if (q < 2 && c + 16 * i < 20) fb[q * 4 + r][c + 16 * i] = h2t[i][r];
  asm volatile("s_waitcnt lgkmcnt(0)" ::: "memory");
  const int e2 = l >> 3, j0 = (l & 7) * 2;
  float a0 = ws[OFF_BD + j0];
  float a1 = (j0 + 1 < 15) ? ws[OFF_BD + j0 + 1] : 0.f;
#pragma unroll
  for (int k = 0; k < 20; ++k) {
    float h = fb[e2][k];
    a0 = fmaf(h, ws[OFF_WD + k * 15 + j0], a0);
    if (j0 + 1 < 15) a1 = fmaf(h, ws[OFF_WD + k * 15 + j0 + 1], a1);
  }
  const size_t ob = (size_t)(wid * 8 + e2) * 15;
  if (isf) {
    ((float*)out)[ob + j0] = a0;
    if (j0 + 1 < 15) ((float*)out)[ob + j0 + 1] = a1;
  } else {
    ((__hip_bfloat16*)out)[ob + j0] = __float2bfloat16(a0);
    if (j0 + 1 < 15) ((__hip_bfloat16*)out)[ob + j0 + 1] = __float2bfloat16(a1);
  }
}

extern "C" void kernel_launch(void* const* d_in, const int* in_sizes, int n_in,
                              void* d_out, int out_size, void* d_ws, size_t ws_size,
                              hipStream_t stream) {
  const int* x    = (const int*)d_in[0];
  const void* emb = d_in[1];
  const void* W1  = d_in[2];
  const void* U1  = d_in[3];
  const void* b1  = d_in[4];
  const void* W2  = d_in[5];
  const void* U2  = d_in[6];
  const void* b2  = d_in[7];
  const void* Wd  = d_in[8];
  const void* bd  = d_in[9];
  float* ws = (float*)d_ws;   // 6.44 MB used (12 MB proven safe)

  build_pre<<<256, 256, 0, stream>>>(emb, W1, b1, U1, W2, U2, b2, Wd, bd, ws);
  gru_main<<<1024, 64, 0, stream>>>(x, ws, emb, d_out);
}

// Round 6
// 262.867 us; speedup vs baseline: 1.1035x; 1.0347x over previous
//
#include <hip/hip_runtime.h>
#include <hip/hip_bf16.h>
#include <hip/hip_fp16.h>

#define SEQ_T 100
#define VOCAB_N 50000

typedef short    sh8 __attribute__((ext_vector_type(8)));   // 8 bf16 bits
typedef _Float16 hf8 __attribute__((ext_vector_type(8)));   // 8 f16
typedef float    f4  __attribute__((ext_vector_type(4)));

// ws layout (dword offsets), total 1,608,271 dwords = 6.44 MB (< 12MB proven)
// B-frags: 30 frags x 1KB. Order: W1kt0 nt0-5 | W1kt1 nt0-5 (bf16) |
//          U1 nt0-5 | W2 nt0-5 | U2 nt0-5 (f16).
// Gate-padded N=96: z cols 0-31 (20 real), r 32-63, h 64-95 -> z,r,h for a
// given (elem,col) sit in the SAME lane of the MFMA D layout.
#define OFF_BF   0
#define OFF_BIAS 7680     // bzr1[64] bxh1[32] brh1[32] bzr2[64] bxh2[32] brh2[32]
#define OFF_WD   7936     // 300
#define OFF_BD   8236     // 15
#define OFF_TABA 8256     // 50000 x 32 dwords: emb rows as bf16 padded to 64 cols

__device__ __forceinline__ float ldf(const void* p, int i, int isf) {
  return isf ? ((const float*)p)[i]
             : __bfloat162float(((const __hip_bfloat16*)p)[i]);
}
__device__ __forceinline__ unsigned short f2bf(float f) {   // RNE fp32->bf16
  unsigned u = __float_as_uint(f);
  u += 0x7fffu + ((u >> 16) & 1u);
  return (unsigned short)(u >> 16);
}
__device__ __forceinline__ int detect_isf(const void* emb) {
  uint4 dv = ((const uint4*)emb)[threadIdx.x & 63];
  int big = 0;
#pragma unroll
  for (int i = 0; i < 4; ++i) {
    unsigned w = ((const unsigned*)&dv)[i];
    big |= (((w >> 7) & 0xFF) >= 140) | (((w >> 23) & 0xFF) >= 140);
  }
  return (__ballot(big) != 0ull) ? 1 : 0;
}
// exact gate primitives (v_exp_f32 = 2^x, v_rcp): bit-match r17/r19
__device__ __forceinline__ float vexp2(float x) {
  float r; asm("v_exp_f32 %0, %1\n\ts_nop 1" : "=v"(r) : "v"(x)); return r;
}
__device__ __forceinline__ float vrcp(float x) {
  float r; asm("v_rcp_f32 %0, %1\n\ts_nop 1" : "=v"(r) : "v"(x)); return r;
}
__device__ __forceinline__ unsigned short cvw(const void* M, int idx, int isf, int fp16) {
  float f = ldf(M, idx, isf);
  return fp16 ? __half_as_ushort(__float2half_rn(f)) : f2bf(f);
}

// Prep: B-frags (gate-padded, MFMA B layout: lane&15=col-n, k=(lane>>4)*8+jj),
// biases (zr gets bi+br; xh gets bi_h, rh br_h), Wd/bd, and tabA = emb rows
// as bf16 padded to 64 cols (A-operand-ready).
__global__ __launch_bounds__(256) void build_pre(
    const void* __restrict__ emb, const void* __restrict__ W1,
    const void* __restrict__ b1,
    const void* __restrict__ U1, const void* __restrict__ W2,
    const void* __restrict__ U2, const void* __restrict__ b2,
    const void* __restrict__ Wd, const void* __restrict__ bd,
    float* __restrict__ ws)
{
  const int isf = detect_isf(emb);
  unsigned* wsu = (unsigned*)ws;
  if (blockIdx.x == 0) {
    for (int i = threadIdx.x; i < 7680; i += 256) {
      const int f = i >> 8, L = (i >> 2) & 63, dw = i & 3;
      const void* M; int kt, nt, kmax, fp16;
      if (f < 6)       { M = W1; kt = 0; nt = f;      kmax = 50; fp16 = 0; }
      else if (f < 12) { M = W1; kt = 1; nt = f - 6;  kmax = 50; fp16 = 0; }
      else if (f < 18) { M = U1; kt = 0; nt = f - 12; kmax = 20; fp16 = 1; }
      else if (f < 24) { M = W2; kt = 0; nt = f - 18; kmax = 20; fp16 = 1; }
      else             { M = U2; kt = 0; nt = f - 24; kmax = 20; fp16 = 1; }
      const int n = nt * 16 + (L & 15);
      const int gc = n < 32 ? n : (n < 64 ? n - 12 : n - 24); // z / r(+20) / h(+40)
      const int gcv = (n & 31) < 20;
      const int k0 = kt * 32 + ((L >> 4) * 8) + dw * 2;
      unsigned lo = 0, hi = 0;
      if (gcv && k0 < kmax)     lo = cvw(M, k0 * 60 + gc, isf, fp16);
      if (gcv && k0 + 1 < kmax) hi = cvw(M, (k0 + 1) * 60 + gc, isf, fp16);
      wsu[OFF_BF + i] = lo | (hi << 16);
    }
    {
      int i = threadIdx.x;                       // 256 bias values, 256 thr
      const int half = i >> 7;
      const void* B = half ? b2 : b1;
      const int n = i & 127;
      float v = 0.f;
      if (n < 64)      { int gc = n < 32 ? n : n - 12;
                         if ((n & 31) < 20) v = ldf(B, gc, isf) + ldf(B, 60 + gc, isf); }
      else if (n < 96) { int cc = n - 64; if (cc < 20) v = ldf(B, 40 + cc, isf); }
      else             { int cc = n - 96; if (cc < 20) v = ldf(B, 100 + cc, isf); }
      ws[OFF_BIAS + i] = v;
    }
    for (int i = threadIdx.x; i < 300; i += 256) ws[OFF_WD + i] = ldf(Wd, i, isf);
    for (int i = threadIdx.x; i < 15;  i += 256) ws[OFF_BD + i] = ldf(bd, i, isf);
  }
  // tabA: 1.6M dwords, coalesced grid-stride. Row = 128B: 25 data dwords + 7 zero.
  const int total = VOCAB_N * 32;
  for (int d = blockIdx.x * 256 + threadIdx.x; d < total; d += 256 * 256) {
    const int row = d >> 5, c2 = d & 31;
    unsigned v = 0;
    if (c2 < 25) {
      if (!isf) v = ((const unsigned*)emb)[row * 25 + c2];
      else {
        const float* ef = (const float*)emb;
        v = (unsigned)f2bf(ef[row * 50 + 2 * c2]) |
            ((unsigned)f2bf(ef[row * 50 + 2 * c2 + 1]) << 16);
      }
    }
    wsu[OFF_TABA + d] = v;
  }
}

// ROUND-20: de-serialize the r19 chain. Measured r19: 4267 cyc/step at 1
// wave/SIMD with only ~600 issue-cyc -> 85% exposed latency. Three fixes:
// (1) UNCONDITIONAL LDS h-writes. The old `if (col<20)` exec-mask dance
//     (v_cmp+saveexec+restore x16/step) is dead weight: B-frags have k>=20
//     rows zeroed, and all h values are finite, so pad-col garbage times
//     zero-frag = exact 0. Plain ds_write_b16, no masks.
// (2) azrP/axhP: E(t)@W1 + bias precomputed ONE STEP AHEAD from prefetched
//     frags -> the h1 recurrence sees a depth-1 MFMA (was depth-3).
// (3) h2a-dependent L2 partials (p2, arh2) computed EARLY (h2a available at
//     step start), overlapping layer 1 -> depth-1 after h1a (was depth-2).
// Accumulate-order change in azr2 (u2 before w2) is ulp-level only.
__global__ __launch_bounds__(64) void gru_main(
    const int* __restrict__ x, const float* __restrict__ ws,
    const void* __restrict__ emb, void* __restrict__ out)
{
  const int isf = detect_isf(emb);            // output dtype only
  const int l = threadIdx.x, c = l & 15, q = l >> 4;
  const int wid = blockIdx.x;

  __shared__ _Float16 hb1[16][40];            // [elem][k] rows padded to 80B
  __shared__ _Float16 hb2[16][40];
  __shared__ float    fb[16][21];
  for (int i = l; i < 640; i += 64) {
    ((_Float16*)hb1)[i] = (_Float16)0.f;
    ((_Float16*)hb2)[i] = (_Float16)0.f;
  }
  asm volatile("s_waitcnt lgkmcnt(0)" ::: "memory");

  const uint4* wsu4 = (const uint4*)ws;
  sh8 w1f[12]; hf8 u1f[6], w2f[6], u2f[6];
#pragma unroll
  for (int f = 0; f < 12; ++f) { uint4 u = wsu4[f * 64 + l];        w1f[f] = *(sh8*)&u; }
#pragma unroll
  for (int f = 0; f < 6; ++f)  { uint4 u = wsu4[(12 + f) * 64 + l]; u1f[f] = *(hf8*)&u; }
#pragma unroll
  for (int f = 0; f < 6; ++f)  { uint4 u = wsu4[(18 + f) * 64 + l]; w2f[f] = *(hf8*)&u; }
#pragma unroll
  for (int f = 0; f < 6; ++f)  { uint4 u = wsu4[(24 + f) * 64 + l]; u2f[f] = *(hf8*)&u; }

  float bzr1[4], bzr2[4], bxh1[2], brh1[2], bxh2[2], brh2[2];
#pragma unroll
  for (int nt = 0; nt < 4; ++nt) {
    bzr1[nt] = ws[OFF_BIAS + nt * 16 + c];
    bzr2[nt] = ws[OFF_BIAS + 128 + nt * 16 + c];
  }
#pragma unroll
  for (int i = 0; i < 2; ++i) {
    bxh1[i] = ws[OFF_BIAS + 64 + i * 16 + c];
    brh1[i] = ws[OFF_BIAS + 96 + i * 16 + c];
    bxh2[i] = ws[OFF_BIAS + 192 + i * 16 + c];
    brh2[i] = ws[OFF_BIAS + 224 + i * 16 + c];
  }

  const uint4* ta = (const uint4*)(ws + OFF_TABA);
  const int* xb = x + (size_t)(wid * 8 + (c & 7)) * SEQ_T;  // A rows 8-15 dup 0-7

  f4 h1t[2] = {{0.f,0.f,0.f,0.f},{0.f,0.f,0.f,0.f}};
  f4 h2t[2] = {{0.f,0.f,0.f,0.f},{0.f,0.f,0.f,0.f}};
  hf8 h1a = {(_Float16)0.f};
  hf8 h2a = {(_Float16)0.f};

  // ---- pre(0): azrP/axhP = bias + E(0)@W1, from frags of x[0] ----
  f4 azrP[4], axhP[2];
  {
    const int x0 = xb[0];
    uint4 fa0 = ta[x0 * 8 + q], fa1 = ta[x0 * 8 + 4 + q];
    const sh8 eA = *(const sh8*)&fa0, eB = *(const sh8*)&fa1;
#pragma unroll
    for (int nt = 0; nt < 4; ++nt) {
      f4 a = { bzr1[nt], bzr1[nt], bzr1[nt], bzr1[nt] };
      a = __builtin_amdgcn_mfma_f32_16x16x32_bf16(eA, w1f[nt], a, 0, 0, 0);
      a = __builtin_amdgcn_mfma_f32_16x16x32_bf16(eB, w1f[6 + nt], a, 0, 0, 0);
      azrP[nt] = a;
    }
#pragma unroll
    for (int i = 0; i < 2; ++i) {
      f4 a = { bxh1[i], bxh1[i], bxh1[i], bxh1[i] };
      a = __builtin_amdgcn_mfma_f32_16x16x32_bf16(eA, w1f[4 + i], a, 0, 0, 0);
      a = __builtin_amdgcn_mfma_f32_16x16x32_bf16(eB, w1f[10 + i], a, 0, 0, 0);
      axhP[i] = a;
    }
  }
  // frags for t=1 in flight; xn = row for t+2 load, x2 = next
  int x1 = xb[1];
  uint4 fa0 = ta[x1 * 8 + q], fa1 = ta[x1 * 8 + 4 + q];
  int xn = xb[2], x2 = xb[3];

  for (int t = 0; t < SEQ_T; ++t) {
    // issue frag loads for t+2 (consumed NEXT iteration's pre-MFMAs)
    uint4 nb0 = ta[xn * 8 + q], nb1 = ta[xn * 8 + 4 + q];
    const int tpp = (t + 4 < SEQ_T) ? t + 4 : SEQ_T - 1;
    const int xnn = xb[tpp];

    // ---- L2 early partials (h2a-dependent only; h2a ready at step start) --
    f4 p2[4], arh2[2];
#pragma unroll
    for (int nt = 0; nt < 4; ++nt) {
      f4 a = { bzr2[nt], bzr2[nt], bzr2[nt], bzr2[nt] };
      p2[nt] = __builtin_amdgcn_mfma_f32_16x16x32_f16(h2a, u2f[nt], a, 0, 0, 0);
    }
#pragma unroll
    for (int i = 0; i < 2; ++i) {
      f4 b = { brh2[i], brh2[i], brh2[i], brh2[i] };
      arh2[i] = __builtin_amdgcn_mfma_f32_16x16x32_f16(h2a, u2f[4 + i], b, 0, 0, 0);
    }

    // ---- layer 1: depth-1 on h1a ----
    f4 azr[4], arh[2];
#pragma unroll
    for (int nt = 0; nt < 4; ++nt)
      azr[nt] = __builtin_amdgcn_mfma_f32_16x16x32_f16(h1a, u1f[nt], azrP[nt], 0, 0, 0);
#pragma unroll
    for (int i = 0; i < 2; ++i) {
      f4 b = { brh1[i], brh1[i], brh1[i], brh1[i] };
      arh[i] = __builtin_amdgcn_mfma_f32_16x16x32_f16(h1a, u1f[4 + i], b, 0, 0, 0);
    }
    // ---- gates layer 1 (lane-local, unconditional LDS writes) ----
#pragma unroll
    for (int i = 0; i < 2; ++i)
#pragma unroll
      for (int r = 0; r < 4; ++r) {
        float z  = vrcp(1.f + vexp2(azr[i][r] * -1.44269504f));
        float rg = vrcp(1.f + vexp2(azr[2 + i][r] * -1.44269504f));
        float hp = fmaf(rg, arh[i][r], axhP[i][r]);
        float hc = fmaf(-2.f, vrcp(1.f + vexp2(hp * 2.88539008f)), 1.f);
        float hn = fmaf(z, h1t[i][r] - hc, hc);
        h1t[i][r] = hn;
        hb1[q * 4 + r][c + 16 * i] = (_Float16)hn;   // pad cols hit zero B-frags
      }
    asm volatile("s_waitcnt lgkmcnt(0)" ::: "memory");
    h1a = *(const hf8*)&hb1[c][q * 8];

    // ---- layer 2 finish: depth-1 on h1a ----
    f4 azr2[4], axh2[2];
#pragma unroll
    for (int nt = 0; nt < 4; ++nt)
      azr2[nt] = __builtin_amdgcn_mfma_f32_16x16x32_f16(h1a, w2f[nt], p2[nt], 0, 0, 0);
#pragma unroll
    for (int i = 0; i < 2; ++i) {
      f4 a = { bxh2[i], bxh2[i], bxh2[i], bxh2[i] };
      axh2[i] = __builtin_amdgcn_mfma_f32_16x16x32_f16(h1a, w2f[4 + i], a, 0, 0, 0);
    }
#pragma unroll
    for (int i = 0; i < 2; ++i)
#pragma unroll
      for (int r = 0; r < 4; ++r) {
        float z  = vrcp(1.f + vexp2(azr2[i][r] * -1.44269504f));
        float rg = vrcp(1.f + vexp2(azr2[2 + i][r] * -1.44269504f));
        float hp = fmaf(rg, arh2[i][r], axh2[i][r]);
        float hc = fmaf(-2.f, vrcp(1.f + vexp2(hp * 2.88539008f)), 1.f);
        float hn = fmaf(z, h2t[i][r] - hc, hc);
        h2t[i][r] = hn;
        hb2[q * 4 + r][c + 16 * i] = (_Float16)hn;
      }
    asm volatile("s_waitcnt lgkmcnt(0)" ::: "memory");
    h2a = *(const hf8*)&hb2[c][q * 8];

    // ---- pre(t+1): from frags loaded LAST iteration (fa0/fa1) ----
    {
      const sh8 eA = *(const sh8*)&fa0, eB = *(const sh8*)&fa1;
#pragma unroll
      for (int nt = 0; nt < 4; ++nt) {
        f4 a = { bzr1[nt], bzr1[nt], bzr1[nt], bzr1[nt] };
        a = __builtin_amdgcn_mfma_f32_16x16x32_bf16(eA, w1f[nt], a, 0, 0, 0);
        a = __builtin_amdgcn_mfma_f32_16x16x32_bf16(eB, w1f[6 + nt], a, 0, 0, 0);
        azrP[nt] = a;
      }
#pragma unroll
      for (int i = 0; i < 2; ++i) {
        f4 a = { bxh1[i], bxh1[i], bxh1[i], bxh1[i] };
        a = __builtin_amdgcn_mfma_f32_16x16x32_bf16(eA, w1f[4 + i], a, 0, 0, 0);
        a = __builtin_amdgcn_mfma_f32_16x16x32_bf16(eB, w1f[10 + i], a, 0, 0, 0);
        axhP[i] = a;
      }
    }
    fa0 = nb0; fa1 = nb1; xn = x2; x2 = xnn;   // rotate prefetch pipeline
  }

  // ---- epilogue: logits = h2 @ Wd + bd via LDS transpose of h2t ----
#pragma unroll
  for (int i = 0; i < 2; ++i)
#pragma unroll
    for (int r = 0; r < 4; ++r)
      if (q < 2 && c + 16 * i < 20) fb[q * 4 + r][c + 16 * i] = h2t[i][r];
  asm volatile("s_waitcnt lgkmcnt(0)" ::: "memory");
  const int e2 = l >> 3, j0 = (l & 7) * 2;
  float a0 = ws[OFF_BD + j0];
  float a1 = (j0 + 1 < 15) ? ws[OFF_BD + j0 + 1] : 0.f;
#pragma unroll
  for (int k = 0; k < 20; ++k) {
    float h = fb[e2][k];
    a0 = fmaf(h, ws[OFF_WD + k * 15 + j0], a0);
    if (j0 + 1 < 15) a1 = fmaf(h, ws[OFF_WD + k * 15 + j0 + 1], a1);
  }
  const size_t ob = (size_t)(wid * 8 + e2) * 15;
  if (isf) {
    ((float*)out)[ob + j0] = a0;
    if (j0 + 1 < 15) ((float*)out)[ob + j0 + 1] = a1;
  } else {
    ((__hip_bfloat16*)out)[ob + j0] = __float2bfloat16(a0);
    if (j0 + 1 < 15) ((__hip_bfloat16*)out)[ob + j0 + 1] = __float2bfloat16(a1);
  }
}

extern "C" void kernel_launch(void* const* d_in, const int* in_sizes, int n_in,
                              void* d_out, int out_size, void* d_ws, size_t ws_size,
                              hipStream_t stream) {
  const int* x    = (const int*)d_in[0];
  const void* emb = d_in[1];
  const void* W1  = d_in[2];
  const void* U1  = d_in[3];
  const void* b1  = d_in[4];
  const void* W2  = d_in[5];
  const void* U2  = d_in[6];
  const void* b2  = d_in[7];
  const void* Wd  = d_in[8];
  const void* bd  = d_in[9];
  float* ws = (float*)d_ws;   // 6.44 MB used (12 MB proven safe)

  build_pre<<<256, 256, 0, stream>>>(emb, W1, b1, U1, W2, U2, b2, Wd, bd, ws);
  gru_main<<<1024, 64, 0, stream>>>(x, ws, emb, d_out);
}

// Round 7
// 243.462 us; speedup vs baseline: 1.1915x; 1.0797x over previous
//
#include <hip/hip_runtime.h>
#include <hip/hip_bf16.h>
#include <hip/hip_fp16.h>

#define SEQ_T 100
#define HID 20
#define EMB_D 50
#define VOCAB_N 50000
#define TABW 60          // tab row stride (floats) = 60 gate cols [z20|r20|h20]
#define NTILE 3125       // VOCAB_N/16
#define BBLK 782         // build_table blocks (x4 waves = 3128 waves, 1 tile/wave)

typedef short sh8 __attribute__((ext_vector_type(8)));   // 8 bf16 bit patterns
typedef float f4  __attribute__((ext_vector_type(4)));

// ws layout (float/dword offsets). TOTAL footprint unchanged: 12,016,640 B.
#define OFF_U1P 0        // 600 dwords (60 cols x 10 packed f16 k-pairs)
#define OFF_W2P 600
#define OFF_U2P 1200
#define OFF_B1  3600     // 120 fp32
#define OFF_B2  3720     // 120 fp32
#define OFF_WD  3840     // 300 fp32
#define OFF_BD  4140     // 15 fp32
#define OFF_TAB 4160     // 50000*60 fp32

__device__ __forceinline__ float ldf(const void* p, int i, int isf) {
  return isf ? ((const float*)p)[i]
             : __bfloat162float(((const __hip_bfloat16*)p)[i]);
}
__device__ __forceinline__ short f2bf(float f) {   // RNE fp32->bf16 bits
  unsigned u = __float_as_uint(f);
  u += 0x7fffu + ((u >> 16) & 1u);
  return (short)(u >> 16);
}
__device__ __forceinline__ float rdl(float v, int l) {
  return __uint_as_float(__builtin_amdgcn_readlane(__float_as_uint(v), l));
}
__device__ __forceinline__ int detect_isf(const void* emb) {
  uint4 dv = ((const uint4*)emb)[threadIdx.x & 63];
  int big = 0;
#pragma unroll
  for (int i = 0; i < 4; ++i) {
    unsigned w = ((const unsigned*)&dv)[i];
    big |= (((w >> 7) & 0xFF) >= 140) | (((w >> 23) & 0xFF) >= 140);
  }
  return (__ballot(big) != 0ull) ? 1 : 0;
}

// tab = emb @ W1 + bi1 on the matrix cores (round-13 structure, verified).
__global__ __launch_bounds__(256) void build_table(
    const void* __restrict__ emb, const void* __restrict__ W1,
    const void* __restrict__ b1,
    const void* __restrict__ U1, const void* __restrict__ W2,
    const void* __restrict__ U2, const void* __restrict__ b2,
    const void* __restrict__ Wd, const void* __restrict__ bd,
    float* __restrict__ ws)
{
  const int isf = detect_isf(emb);
  if (blockIdx.x == 0) {                     // fold: weight prep
    const int t = threadIdx.x;
    unsigned* wsu = (unsigned*)ws;
    for (int i = t; i < 600; i += 256) {
      const int j = i / 10, p = i % 10;
      const int k0 = 2 * p, k1 = 2 * p + 1;
#define PK(M) ((unsigned)__half_as_ushort(__float2half_rn(ldf(M, k0 * 60 + j, isf))) | \
               ((unsigned)__half_as_ushort(__float2half_rn(ldf(M, k1 * 60 + j, isf))) << 16))
      wsu[OFF_U1P + i] = PK(U1);
      wsu[OFF_W2P + i] = PK(W2);
      wsu[OFF_U2P + i] = PK(U2);
#undef PK
    }
    for (int i = t; i < 120; i += 256) {
      ws[OFF_B1 + i] = ldf(b1, i, isf);
      ws[OFF_B2 + i] = ldf(b2, i, isf);
    }
    for (int i = t; i < 300; i += 256) ws[OFF_WD + i] = ldf(Wd, i, isf);
    for (int i = t; i < 15;  i += 256) ws[OFF_BD + i] = ldf(bd, i, isf);
  }

  const int L = threadIdx.x & 63, q = L >> 4, c = L & 15;
  const int wid = blockIdx.x * 4 + (threadIdx.x >> 6);
  float* __restrict__ tab = ws + OFF_TAB;

  __shared__ int4 sB[64][8];
  if (threadIdx.x < 64) {
#pragma unroll
    for (int nt = 0; nt < 4; ++nt) {
      const int col = nt * 16 + c;
      sh8 B0, B1;
#pragma unroll
      for (int jj = 0; jj < 8; ++jj) {
        const int k0 = q * 8 + jj, k1 = 32 + q * 8 + jj;
        B0[jj] = (col < TABW) ? f2bf(ldf(W1, k0 * TABW + col, isf)) : (short)0;
        B1[jj] = (col < TABW && k1 < EMB_D)
                     ? f2bf(ldf(W1, k1 * TABW + col, isf)) : (short)0;
      }
      sB[L][nt * 2]     = *(const int4*)&B0;
      sB[L][nt * 2 + 1] = *(const int4*)&B1;
    }
  }
  float bi[4];
#pragma unroll
  for (int nt = 0; nt < 4; ++nt) {
    const int col = nt * 16 + c;
    bi[nt] = (col < TABW) ? ldf(b1, col, isf) : 0.f;
  }
  __syncthreads();

  for (int tile = wid; tile < NTILE; tile += BBLK * 4) {
    const int v0 = tile * 16;
    sh8 A0, A1;
#pragma unroll
    for (int jj = 0; jj < 8; ++jj) { A0[jj] = 0; A1[jj] = 0; }
    if (!isf) {
      const unsigned short* eb = (const unsigned short*)emb;
      const size_t rb = (size_t)(v0 + c) * EMB_D;
#pragma unroll
      for (int i = 0; i < 4; ++i) {
        unsigned d = *(const unsigned*)(eb + rb + q * 8 + 2 * i);
        A0[2 * i] = (short)(d & 0xffff); A0[2 * i + 1] = (short)(d >> 16);
      }
      const int k1b = 32 + q * 8;
#pragma unroll
      for (int i = 0; i < 4; ++i) {
        const int k = k1b + 2 * i;
        if (k + 1 < EMB_D) {
          unsigned d = *(const unsigned*)(eb + rb + k);
          A1[2 * i] = (short)(d & 0xffff); A1[2 * i + 1] = (short)(d >> 16);
        }
      }
    } else {
      const float* ef = (const float*)emb;
      const size_t rb = (size_t)(v0 + c) * EMB_D;
#pragma unroll
      for (int jj = 0; jj < 8; ++jj) {
        const int k0 = q * 8 + jj, k1 = 32 + q * 8 + jj;
        A0[jj] = f2bf(ef[rb + k0]);
        A1[jj] = (k1 < EMB_D) ? f2bf(ef[rb + k1]) : (short)0;
      }
    }
#pragma unroll
    for (int nt = 0; nt < 4; ++nt) {
      int4 b0i = sB[L][nt * 2], b1i = sB[L][nt * 2 + 1];
      sh8 B0 = *(const sh8*)&b0i, B1 = *(const sh8*)&b1i;
      const int col = nt * 16 + c;
      f4 acc = { bi[nt], bi[nt], bi[nt], bi[nt] };
      acc = __builtin_amdgcn_mfma_f32_16x16x32_bf16(A0, B0, acc, 0, 0, 0);
      acc = __builtin_amdgcn_mfma_f32_16x16x32_bf16(A1, B1, acc, 0, 0, 0);
      if (col < TABW) {
#pragma unroll
        for (int r = 0; r < 4; ++r)
          tab[(size_t)(v0 + q * 4 + r) * TABW + col] = acc[r];
      }
    }
  }
}

// ONE batch element per wave; 100-step GRU in inline asm (r17 base, 153us).
// ROUND-21: DS 3->1 per elem-step via lane REASSIGNMENT (dots unchanged).
// r17's 3672 cyc/step is a multi-pipe composite; the shared per-CU DS pipe
// (96 wave64 bpermute/swizzle per step at 32 waves/CU) is its largest term.
// r18 proved permlane32_swap-max and DPP quad_perm are numerically correct
// but lost by doubling dot chains; this round keeps ONE chain and only
// remaps lanes: z cols->lanes 0-19, h cols->lanes 32-51, r cols->lanes
// 20-31 (c0-11) + 52-59 (c12-19). Consequences: hc never moves (update in
// h-lanes); z->h is exactly lane+-32 = permlane32_swap (VALU); neighbor
// pack is DPP quad_perm; only rr->h (irregular -12/+8) stays ds_bpermute.
__global__ __launch_bounds__(256, 8) void gru_main(
    const int* __restrict__ x, const float* __restrict__ ws,
    const void* __restrict__ emb, void* __restrict__ out)
{
  const int isf = detect_isf(emb);   // output dtype only
  const int j = threadIdx.x & 63;
  const int e = __builtin_amdgcn_readfirstlane(blockIdx.x * 4 + (threadIdx.x >> 6));

  // lane -> gate-column map (tab order z0-19|r20-39|h40-59):
  int jc;
  if (j < 32)      jc = j;        // z cols (0-19), r cols 0-11 (lanes 20-31)
  else if (j < 52) jc = j + 8;    // h cols 0-19 -> tab 40..59
  else if (j < 60) jc = j - 20;   // r cols 12-19 -> tab 32..39
  else             jc = 0;

  const int* xr = x + (size_t)e * SEQ_T;
  const float* tab = ws + OFF_TAB;
  const int o1 = jc * 40;                    // 10 packed dwords per column
  const int jc4 = jc * 4;                    // byte offset of col jc in tab row
  int src = 0;                               // bpermute: h-lane pulls its r
  if (j >= 32 && j < 52) { int cc = j - 32; src = (cc < 12) ? 20 + cc : 40 + cc; }
  const int a1 = src * 4;
  const float br1 = ws[OFF_B1 + 60 + jc];
  const float bi2 = ws[OFF_B2 + jc];
  const float br2 = ws[OFF_B2 + 60 + jc];
  float h2out;

  asm volatile(
    // ---- packed f16 weights: U1P v10-19, W2P v20-29, U2P v30-39 ----
    "global_load_dwordx4 v[10:13], %[o1], %[wsp] offset:0\n\t"
    "global_load_dwordx4 v[14:17], %[o1], %[wsp] offset:16\n\t"
    "global_load_dwordx2 v[18:19], %[o1], %[wsp] offset:32\n\t"
    "v_add_u32 v44, 0x960, %[o1]\n\t"
    "v_add_u32 v45, 0x12c0, %[o1]\n\t"
    "global_load_dwordx4 v[20:23], v44, %[wsp] offset:0\n\t"
    "global_load_dwordx4 v[24:27], v44, %[wsp] offset:16\n\t"
    "global_load_dwordx2 v[28:29], v44, %[wsp] offset:32\n\t"
    "global_load_dwordx4 v[30:33], v45, %[wsp] offset:0\n\t"
    "global_load_dwordx4 v[34:37], v45, %[wsp] offset:16\n\t"
    "global_load_dwordx2 v[38:39], v45, %[wsp] offset:32\n\t"
    // ---- z-lane mask (lanes 0-19) for permlane max-trick ----
    "s_mov_b32 s60, 0xfffff\n\t"
    "s_mov_b32 s61, 0\n\t"
    // ---- h state zero: h1 sets s20-29/s40-49, h2 sets s30-39/s50-59 ----
    "s_mov_b64 s[20:21], 0\n\ts_mov_b64 s[22:23], 0\n\t"
    "s_mov_b64 s[24:25], 0\n\ts_mov_b64 s[26:27], 0\n\t"
    "s_mov_b64 s[28:29], 0\n\t"
    "s_mov_b64 s[30:31], 0\n\ts_mov_b64 s[32:33], 0\n\t"
    "s_mov_b64 s[34:35], 0\n\ts_mov_b64 s[36:37], 0\n\t"
    "s_mov_b64 s[38:39], 0\n\t"
    "s_mov_b64 s[40:41], 0\n\ts_mov_b64 s[42:43], 0\n\t"
    "s_mov_b64 s[44:45], 0\n\ts_mov_b64 s[46:47], 0\n\t"
    "s_mov_b64 s[48:49], 0\n\t"
    "s_mov_b64 s[50:51], 0\n\ts_mov_b64 s[52:53], 0\n\t"
    "s_mov_b64 s[54:55], 0\n\ts_mov_b64 s[56:57], 0\n\t"
    "s_mov_b64 s[58:59], 0\n\t"
    "v_mov_b32 v40, 0\n\t"
    "v_mov_b32 v41, 0\n\t"
    // ---- prime: mx0->v53, mx1->v42, mx2->v43; idx3->s65, idx4->s68 ----
    "s_load_dword s65, %[xp], 0x0\n\t"
    "s_load_dword s66, %[xp], 0x4\n\t"
    "s_load_dword s68, %[xp], 0x8\n\t"
    "s_waitcnt lgkmcnt(0)\n\t"
    "s_mul_i32 s65, s65, 240\n\t"
    "s_mul_i32 s66, s66, 240\n\t"
    "s_mul_i32 s68, s68, 240\n\t"
    "v_add_u32 v50, s65, %[jc4]\n\t"
    "global_load_dword v53, v50, %[tabp]\n\t"
    "v_add_u32 v50, s66, %[jc4]\n\t"
    "global_load_dword v42, v50, %[tabp]\n\t"
    "v_add_u32 v50, s68, %[jc4]\n\t"
    "global_load_dword v43, v50, %[tabp]\n\t"
    "s_load_dword s65, %[xp], 0xc\n\t"     // idx3 (odd stream)
    "s_load_dword s68, %[xp], 0x10\n\t"    // idx4 (even stream)
    "s_movk_i32 s64, 0x14\n\t"             // next odd x-offset (idx5)
    "s_movk_i32 s69, 0x18\n\t"             // next even x-offset (idx6)
    "s_movk_i32 s67, 0x32\n\t"             // 50 unrolled iterations
    "s_waitcnt vmcnt(2)\n\t"               // mx0 + all weights ready
    // ======== PROLOGUE: L1(0)  (h1(-1)=s40-49 zeros, mx0=v53) ========
    "v_mov_b32 v44, %[br1]\n\t"
    "v_dot2_f32_f16 v44, s40, v10, v44\n\t"
    "v_dot2_f32_f16 v44, s41, v11, v44\n\t"
    "v_dot2_f32_f16 v44, s42, v12, v44\n\t"
    "v_dot2_f32_f16 v44, s43, v13, v44\n\t"
    "v_dot2_f32_f16 v44, s44, v14, v44\n\t"
    "v_dot2_f32_f16 v44, s45, v15, v44\n\t"
    "v_dot2_f32_f16 v44, s46, v16, v44\n\t"
    "v_dot2_f32_f16 v44, s47, v17, v44\n\t"
    "v_dot2_f32_f16 v44, s48, v18, v44\n\t"
    "v_dot2_f32_f16 v44, s49, v19, v44\n\t"
    "v_add_f32 v45, v53, v44\n\t"
    "v_mul_f32 v45, 0xbfb8aa3b, v45\n\t"
    "v_exp_f32 v45, v45\n\t"
    "s_nop 1\n\t"
    "v_add_f32 v45, 1.0, v45\n\t"
    "v_rcp_f32 v45, v45\n\t"
    "s_nop 1\n\t"
    "ds_bpermute_b32 v46, %[a1], v45\n\t"  // rr -> h-lanes
    "s_waitcnt lgkmcnt(0)\n\t"
    "v_fma_f32 v47, v46, v44, v53\n\t"     // hp (h-lanes)
    "v_mul_f32 v47, 0x4038aa3b, v47\n\t"
    "v_exp_f32 v47, v47\n\t"
    "s_nop 1\n\t"
    "v_add_f32 v47, 1.0, v47\n\t"
    "v_rcp_f32 v47, v47\n\t"
    "s_nop 1\n\t"
    "v_fma_f32 v47, -2.0, v47, 1.0\n\t"    // hc (h-lanes)
    "v_cndmask_b32 v46, -4.0, v45, s[60:61]\n\t"  // keep z-lanes
    "v_mov_b32 v48, v46\n\t"
    "s_nop 1\n\t"
    "v_permlane32_swap_b32 v46, v48\n\t"
    "s_nop 1\n\t"
    "v_max_f32 v46, v46, v48\n\t"          // z in h-lanes
    "v_sub_f32 v48, v40, v47\n\t"
    "v_fma_f32 v40, v46, v48, v47\n\t"     // h1(0) (h-lanes)
    "v_cvt_f16_f32 v46, v40\n\t"
    "s_nop 1\n\t"
    "v_mov_b32_dpp v48, v46 quad_perm:[1,0,3,2] row_mask:0xf bank_mask:0xf\n\t"
    "s_nop 1\n\t"
    "v_pack_b32_f16 v46, v46, v48\n\t"
    "s_nop 1\n\t"
    "v_readlane_b32 s20, v46, 32\n\t"
    "v_readlane_b32 s21, v46, 34\n\t"
    "v_readlane_b32 s22, v46, 36\n\t"
    "v_readlane_b32 s23, v46, 38\n\t"
    "v_readlane_b32 s24, v46, 40\n\t"
    "v_readlane_b32 s25, v46, 42\n\t"
    "v_readlane_b32 s26, v46, 44\n\t"
    "v_readlane_b32 s27, v46, 46\n\t"
    "v_readlane_b32 s28, v46, 48\n\t"
    "v_readlane_b32 s29, v46, 50\n\t"
    // ======== LOOP k=0..49 ========
    "0:\n\t"
    // ---- HALF A: L2(2k) || L1(2k+1). read {H1e s20-29, H2o s50-59},
    //      write {H2e s30-39, H1o s40-49}. mx = v42.
    "v_mov_b32 v44, %[br1]\n\t"
    "v_mov_b32 v51, %[bi2]\n\t"
    "v_mov_b32 v52, %[br2]\n\t"
    "v_dot2_f32_f16 v44, s20, v10, v44\n\t"
    "v_dot2_f32_f16 v51, s20, v20, v51\n\t"
    "v_dot2_f32_f16 v52, s50, v30, v52\n\t"
    "v_dot2_f32_f16 v44, s21, v11, v44\n\t"
    "v_dot2_f32_f16 v51, s21, v21, v51\n\t"
    "v_dot2_f32_f16 v52, s51, v31, v52\n\t"
    "v_dot2_f32_f16 v44, s22, v12, v44\n\t"
    "v_dot2_f32_f16 v51, s22, v22, v51\n\t"
    "v_dot2_f32_f16 v52, s52, v32, v52\n\t"
    "v_dot2_f32_f16 v44, s23, v13, v44\n\t"
    "v_dot2_f32_f16 v51, s23, v23, v51\n\t"
    "v_dot2_f32_f16 v52, s53, v33, v52\n\t"
    "v_dot2_f32_f16 v44, s24, v14, v44\n\t"
    "v_dot2_f32_f16 v51, s24, v24, v51\n\t"
    "v_dot2_f32_f16 v52, s54, v34, v52\n\t"
    "v_dot2_f32_f16 v44, s25, v15, v44\n\t"
    "v_dot2_f32_f16 v51, s25, v25, v51\n\t"
    "v_dot2_f32_f16 v52, s55, v35, v52\n\t"
    "v_dot2_f32_f16 v44, s26, v16, v44\n\t"
    "v_dot2_f32_f16 v51, s26, v26, v51\n\t"
    "v_dot2_f32_f16 v52, s56, v36, v52\n\t"
    "v_dot2_f32_f16 v44, s27, v17, v44\n\t"
    "v_dot2_f32_f16 v51, s27, v27, v51\n\t"
    "v_dot2_f32_f16 v52, s57, v37, v52\n\t"
    "v_dot2_f32_f16 v44, s28, v18, v44\n\t"
    "v_dot2_f32_f16 v51, s28, v28, v51\n\t"
    "v_dot2_f32_f16 v52, s58, v38, v52\n\t"
    "v_dot2_f32_f16 v44, s29, v19, v44\n\t"
    "v_dot2_f32_f16 v51, s29, v29, v51\n\t"
    "v_dot2_f32_f16 v52, s59, v39, v52\n\t"
    "s_waitcnt vmcnt(1)\n\t"               // mx(2k+1) in v42
    "v_add_f32 v45, v42, v44\n\t"
    "v_add_f32 v53, v51, v52\n\t"
    "v_mul_f32 v45, 0xbfb8aa3b, v45\n\t"
    "v_mul_f32 v53, 0xbfb8aa3b, v53\n\t"
    "v_exp_f32 v45, v45\n\t"
    "v_exp_f32 v53, v53\n\t"
    "v_add_f32 v45, 1.0, v45\n\t"
    "v_add_f32 v53, 1.0, v53\n\t"
    "v_rcp_f32 v45, v45\n\t"
    "v_rcp_f32 v53, v53\n\t"
    "ds_bpermute_b32 v46, %[a1], v45\n\t"  // rr1 -> h-lanes
    "ds_bpermute_b32 v54, %[a1], v53\n\t"  // rr2 -> h-lanes
    "s_mul_i32 s66, s65, 240\n\t"
    "v_add_u32 v50, s66, %[jc4]\n\t"
    "s_waitcnt lgkmcnt(0)\n\t"
    "v_fma_f32 v47, v46, v44, v42\n\t"     // hp1, last v42 use
    "v_fma_f32 v55, v54, v52, v51\n\t"     // hp2
    "global_load_dword v42, v50, %[tabp]\n\t"  // mx(2k+3)
    "s_min_u32 s64, s64, 396\n\t"
    "s_load_dword s65, %[xp], s64\n\t"     // idx(2k+5)
    "s_add_u32 s64, s64, 8\n\t"
    "v_mul_f32 v47, 0x4038aa3b, v47\n\t"
    "v_mul_f32 v55, 0x4038aa3b, v55\n\t"
    "v_exp_f32 v47, v47\n\t"
    "v_exp_f32 v55, v55\n\t"
    "v_add_f32 v47, 1.0, v47\n\t"
    "v_add_f32 v55, 1.0, v55\n\t"
    "v_rcp_f32 v47, v47\n\t"
    "v_rcp_f32 v55, v55\n\t"
    "s_nop 0\n\t"
    "v_fma_f32 v47, -2.0, v47, 1.0\n\t"    // hc1 (h-lanes)
    "v_fma_f32 v55, -2.0, v55, 1.0\n\t"    // hc2 (h-lanes)
    "v_cndmask_b32 v46, -4.0, v45, s[60:61]\n\t"
    "v_cndmask_b32 v54, -4.0, v53, s[60:61]\n\t"
    "v_mov_b32 v48, v46\n\t"
    "v_mov_b32 v59, v54\n\t"
    "s_nop 1\n\t"
    "v_permlane32_swap_b32 v46, v48\n\t"
    "v_permlane32_swap_b32 v54, v59\n\t"
    "s_nop 1\n\t"
    "v_max_f32 v46, v46, v48\n\t"          // z1 in h-lanes
    "v_max_f32 v54, v54, v59\n\t"          // z2 in h-lanes
    "v_sub_f32 v48, v40, v47\n\t"
    "v_fma_f32 v40, v46, v48, v47\n\t"     // h1(2k+1)
    "v_sub_f32 v48, v41, v55\n\t"
    "v_fma_f32 v41, v54, v48, v55\n\t"     // h2(2k)
    "v_cvt_f16_f32 v46, v40\n\t"
    "v_cvt_f16_f32 v47, v41\n\t"
    "s_nop 1\n\t"
    "v_mov_b32_dpp v48, v46 quad_perm:[1,0,3,2] row_mask:0xf bank_mask:0xf\n\t"
    "v_mov_b32_dpp v49, v47 quad_perm:[1,0,3,2] row_mask:0xf bank_mask:0xf\n\t"
    "s_nop 1\n\t"
    "v_pack_b32_f16 v46, v46, v48\n\t"
    "v_pack_b32_f16 v47, v47, v49\n\t"
    "s_nop 1\n\t"
    "v_readlane_b32 s40, v46, 32\n\t"
    "v_readlane_b32 s41, v46, 34\n\t"
    "v_readlane_b32 s42, v46, 36\n\t"
    "v_readlane_b32 s43, v46, 38\n\t"
    "v_readlane_b32 s44, v46, 40\n\t"
    "v_readlane_b32 s45, v46, 42\n\t"
    "v_readlane_b32 s46, v46, 44\n\t"
    "v_readlane_b32 s47, v46, 46\n\t"
    "v_readlane_b32 s48, v46, 48\n\t"
    "v_readlane_b32 s49, v46, 50\n\t"
    "v_readlane_b32 s30, v47, 32\n\t"
    "v_readlane_b32 s31, v47, 34\n\t"
    "v_readlane_b32 s32, v47, 36\n\t"
    "v_readlane_b32 s33, v47, 38\n\t"
    "v_readlane_b32 s34, v47, 40\n\t"
    "v_readlane_b32 s35, v47, 42\n\t"
    "v_readlane_b32 s36, v47, 44\n\t"
    "v_readlane_b32 s37, v47, 46\n\t"
    "v_readlane_b32 s38, v47, 48\n\t"
    "v_readlane_b32 s39, v47, 50\n\t"
    // ---- HALF B: L2(2k+1) || L1(2k+2). read {H1o s40-49, H2e s30-39},
    //      write {H2o s50-59, H1e s20-29}. mx = v43.
    "v_mov_b32 v44, %[br1]\n\t"
    "v_mov_b32 v51, %[bi2]\n\t"
    "v_mov_b32 v52, %[br2]\n\t"
    "v_dot2_f32_f16 v44, s40, v10, v44\n\t"
    "v_dot2_f32_f16 v51, s40, v20, v51\n\t"
    "v_dot2_f32_f16 v52, s30, v30, v52\n\t"
    "v_dot2_f32_f16 v44, s41, v11, v44\n\t"
    "v_dot2_f32_f16 v51, s41, v21, v51\n\t"
    "v_dot2_f32_f16 v52, s31, v31, v52\n\t"
    "v_dot2_f32_f16 v44, s42, v12, v44\n\t"
    "v_dot2_f32_f16 v51, s42, v22, v51\n\t"
    "v_dot2_f32_f16 v52, s32, v32, v52\n\t"
    "v_dot2_f32_f16 v44, s43, v13, v44\n\t"
    "v_dot2_f32_f16 v51, s43, v23, v51\n\t"
    "v_dot2_f32_f16 v52, s33, v33, v52\n\t"
    "v_dot2_f32_f16 v44, s44, v14, v44\n\t"
    "v_dot2_f32_f16 v51, s44, v24, v51\n\t"
    "v_dot2_f32_f16 v52, s34, v34, v52\n\t"
    "v_dot2_f32_f16 v44, s45, v15, v44\n\t"
    "v_dot2_f32_f16 v51, s45, v25, v51\n\t"
    "v_dot2_f32_f16 v52, s35, v35, v52\n\t"
    "v_dot2_f32_f16 v44, s46, v16, v44\n\t"
    "v_dot2_f32_f16 v51, s46, v26, v51\n\t"
    "v_dot2_f32_f16 v52, s36, v36, v52\n\t"
    "v_dot2_f32_f16 v44, s47, v17, v44\n\t"
    "v_dot2_f32_f16 v51, s47, v27, v51\n\t"
    "v_dot2_f32_f16 v52, s37, v37, v52\n\t"
    "v_dot2_f32_f16 v44, s48, v18, v44\n\t"
    "v_dot2_f32_f16 v51, s48, v28, v51\n\t"
    "v_dot2_f32_f16 v52, s38, v38, v52\n\t"
    "v_dot2_f32_f16 v44, s49, v19, v44\n\t"
    "v_dot2_f32_f16 v51, s49, v29, v51\n\t"
    "v_dot2_f32_f16 v52, s39, v39, v52\n\t"
    "s_waitcnt vmcnt(1)\n\t"               // mx(2k+2) in v43
    "v_add_f32 v45, v43, v44\n\t"
    "v_add_f32 v53, v51, v52\n\t"
    "v_mul_f32 v45, 0xbfb8aa3b, v45\n\t"
    "v_mul_f32 v53, 0xbfb8aa3b, v53\n\t"
    "v_exp_f32 v45, v45\n\t"
    "v_exp_f32 v53, v53\n\t"
    "v_add_f32 v45, 1.0, v45\n\t"
    "v_add_f32 v53, 1.0, v53\n\t"
    "v_rcp_f32 v45, v45\n\t"
    "v_rcp_f32 v53, v53\n\t"
    "ds_bpermute_b32 v46, %[a1], v45\n\t"
    "ds_bpermute_b32 v54, %[a1], v53\n\t"
    "s_mul_i32 s66, s68, 240\n\t"
    "v_add_u32 v50, s66, %[jc4]\n\t"
    "s_waitcnt lgkmcnt(0)\n\t"
    "v_fma_f32 v47, v46, v44, v43\n\t"     // hp1, last v43 use
    "v_fma_f32 v55, v54, v52, v51\n\t"     // hp2
    "global_load_dword v43, v50, %[tabp]\n\t"  // mx(2k+4)
    "s_min_u32 s69, s69, 392\n\t"
    "s_load_dword s68, %[xp], s69\n\t"     // idx(2k+6)
    "s_add_u32 s69, s69, 8\n\t"
    "v_mul_f32 v47, 0x4038aa3b, v47\n\t"
    "v_mul_f32 v55, 0x4038aa3b, v55\n\t"
    "v_exp_f32 v47, v47\n\t"
    "v_exp_f32 v55, v55\n\t"
    "v_add_f32 v47, 1.0, v47\n\t"
    "v_add_f32 v55, 1.0, v55\n\t"
    "v_rcp_f32 v47, v47\n\t"
    "v_rcp_f32 v55, v55\n\t"
    "s_nop 0\n\t"
    "v_fma_f32 v47, -2.0, v47, 1.0\n\t"
    "v_fma_f32 v55, -2.0, v55, 1.0\n\t"
    "v_cndmask_b32 v46, -4.0, v45, s[60:61]\n\t"
    "v_cndmask_b32 v54, -4.0, v53, s[60:61]\n\t"
    "v_mov_b32 v48, v46\n\t"
    "v_mov_b32 v59, v54\n\t"
    "s_nop 1\n\t"
    "v_permlane32_swap_b32 v46, v48\n\t"
    "v_permlane32_swap_b32 v54, v59\n\t"
    "s_nop 1\n\t"
    "v_max_f32 v46, v46, v48\n\t"
    "v_max_f32 v54, v54, v59\n\t"
    "v_sub_f32 v48, v40, v47\n\t"
    "v_fma_f32 v40, v46, v48, v47\n\t"     // h1(2k+2)
    "v_sub_f32 v48, v41, v55\n\t"
    "v_fma_f32 v41, v54, v48, v55\n\t"     // h2(2k+1)
    "v_cvt_f16_f32 v46, v40\n\t"
    "v_cvt_f16_f32 v47, v41\n\t"
    "s_nop 1\n\t"
    "v_mov_b32_dpp v48, v46 quad_perm:[1,0,3,2] row_mask:0xf bank_mask:0xf\n\t"
    "v_mov_b32_dpp v49, v47 quad_perm:[1,0,3,2] row_mask:0xf bank_mask:0xf\n\t"
    "s_nop 1\n\t"
    "v_pack_b32_f16 v46, v46, v48\n\t"
    "v_pack_b32_f16 v47, v47, v49\n\t"
    "s_nop 1\n\t"
    "v_readlane_b32 s20, v46, 32\n\t"
    "v_readlane_b32 s21, v46, 34\n\t"
    "v_readlane_b32 s22, v46, 36\n\t"
    "v_readlane_b32 s23, v46, 38\n\t"
    "v_readlane_b32 s24, v46, 40\n\t"
    "v_readlane_b32 s25, v46, 42\n\t"
    "v_readlane_b32 s26, v46, 44\n\t"
    "v_readlane_b32 s27, v46, 46\n\t"
    "v_readlane_b32 s28, v46, 48\n\t"
    "v_readlane_b32 s29, v46, 50\n\t"
    "v_readlane_b32 s50, v47, 32\n\t"
    "v_readlane_b32 s51, v47, 34\n\t"
    "v_readlane_b32 s52, v47, 36\n\t"
    "v_readlane_b32 s53, v47, 38\n\t"
    "v_readlane_b32 s54, v47, 40\n\t"
    "v_readlane_b32 s55, v47, 42\n\t"
    "v_readlane_b32 s56, v47, 44\n\t"
    "v_readlane_b32 s57, v47, 46\n\t"
    "v_readlane_b32 s58, v47, 48\n\t"
    "v_readlane_b32 s59, v47, 50\n\t"
    "s_sub_u32 s67, s67, 1\n\t"
    "s_cmp_lg_u32 s67, 0\n\t"
    "s_cbranch_scc1 0b\n\t"
    "s_waitcnt vmcnt(0) lgkmcnt(0)\n\t"
    "v_mov_b32 %[h2o], v41\n\t"
    : [h2o] "=v"(h2out)
    : [wsp] "s"(ws), [xp] "s"(xr), [tabp] "s"(tab),
      [o1] "v"(o1), [jc4] "v"(jc4), [a1] "v"(a1),
      [br1] "v"(br1), [bi2] "v"(bi2), [br2] "v"(br2)
    : "memory", "vcc", "scc",
      "v10","v11","v12","v13","v14","v15","v16","v17","v18","v19",
      "v20","v21","v22","v23","v24","v25","v26","v27","v28","v29",
      "v30","v31","v32","v33","v34","v35","v36","v37","v38","v39",
      "v40","v41","v42","v43","v44","v45","v46","v47","v48","v49","v50",
      "v51","v52","v53","v54","v55","v59",
      "s20","s21","s22","s23","s24","s25","s26","s27","s28","s29",
      "s30","s31","s32","s33","s34","s35","s36","s37","s38","s39",
      "s40","s41","s42","s43","s44","s45","s46","s47","s48","s49",
      "s50","s51","s52","s53","s54","s55","s56","s57","s58","s59",
      "s60","s61","s64","s65","s66","s67","s68","s69");

  // ---- dense: logits = h2 @ Wd + bd (h2 master in h-lanes 32..51) ----
  if (j < 15) {
    float a = ws[OFF_BD + j];
#pragma unroll
    for (int k = 0; k < HID; ++k)
      a = fmaf(rdl(h2out, 32 + k), ws[OFF_WD + k * 15 + j], a);
    if (isf) ((float*)out)[(size_t)e * 15 + j] = a;
    else ((__hip_bfloat16*)out)[(size_t)e * 15 + j] = __float2bfloat16(a);
  }
}

extern "C" void kernel_launch(void* const* d_in, const int* in_sizes, int n_in,
                              void* d_out, int out_size, void* d_ws, size_t ws_size,
                              hipStream_t stream) {
  const int* x    = (const int*)d_in[0];
  const void* emb = d_in[1];
  const void* W1  = d_in[2];
  const void* U1  = d_in[3];
  const void* b1  = d_in[4];
  const void* W2  = d_in[5];
  const void* U2  = d_in[6];
  const void* b2  = d_in[7];
  const void* Wd  = d_in[8];
  const void* bd  = d_in[9];
  float* ws = (float*)d_ws;   // 12,016,640 B used (proven safe)

  build_table<<<BBLK, 256, 0, stream>>>(
      emb, W1, b1, U1, W2, U2, b2, Wd, bd, ws);
  gru_main<<<2048, 256, 0, stream>>>(x, ws, emb, d_out);
}

// Round 8
// 202.767 us; speedup vs baseline: 1.4306x; 1.2007x over previous
//
#include <hip/hip_runtime.h>
#include <hip/hip_bf16.h>
#include <hip/hip_fp16.h>

#define SEQ_T 100
#define HID 20
#define EMB_D 50
#define VOCAB_N 50000
#define TABW 60          // tab row stride (floats) = 60 gate cols [z20|r20|h20]
#define NTILE 3125       // VOCAB_N/16
#define BBLK 782         // build_table blocks (x4 waves = 3128 waves, 1 tile/wave)

typedef short sh8 __attribute__((ext_vector_type(8)));   // 8 bf16 bit patterns
typedef float f4  __attribute__((ext_vector_type(4)));

// ws layout (float/dword offsets). TOTAL footprint unchanged: 12,016,640 B.
#define OFF_U1P 0        // 600 dwords (60 cols x 10 packed f16 k-pairs)
#define OFF_W2P 600
#define OFF_U2P 1200
#define OFF_B1  3600     // 120 fp32
#define OFF_B2  3720     // 120 fp32
#define OFF_WD  3840     // 300 fp32
#define OFF_BD  4140     // 15 fp32
#define OFF_TAB 4160     // 50000*60 fp32

__device__ __forceinline__ float ldf(const void* p, int i, int isf) {
  return isf ? ((const float*)p)[i]
             : __bfloat162float(((const __hip_bfloat16*)p)[i]);
}
__device__ __forceinline__ short f2bf(float f) {   // RNE fp32->bf16 bits
  unsigned u = __float_as_uint(f);
  u += 0x7fffu + ((u >> 16) & 1u);
  return (short)(u >> 16);
}
__device__ __forceinline__ float rdl(float v, int l) {
  return __uint_as_float(__builtin_amdgcn_readlane(__float_as_uint(v), l));
}
__device__ __forceinline__ int detect_isf(const void* emb) {
  uint4 dv = ((const uint4*)emb)[threadIdx.x & 63];
  int big = 0;
#pragma unroll
  for (int i = 0; i < 4; ++i) {
    unsigned w = ((const unsigned*)&dv)[i];
    big |= (((w >> 7) & 0xFF) >= 140) | (((w >> 23) & 0xFF) >= 140);
  }
  return (__ballot(big) != 0ull) ? 1 : 0;
}

// tab = emb @ W1 + bi1 on the matrix cores (round-13 structure, verified).
__global__ __launch_bounds__(256) void build_table(
    const void* __restrict__ emb, const void* __restrict__ W1,
    const void* __restrict__ b1,
    const void* __restrict__ U1, const void* __restrict__ W2,
    const void* __restrict__ U2, const void* __restrict__ b2,
    const void* __restrict__ Wd, const void* __restrict__ bd,
    float* __restrict__ ws)
{
  const int isf = detect_isf(emb);
  if (blockIdx.x == 0) {                     // fold: weight prep
    const int t = threadIdx.x;
    unsigned* wsu = (unsigned*)ws;
    for (int i = t; i < 600; i += 256) {
      const int j = i / 10, p = i % 10;
      const int k0 = 2 * p, k1 = 2 * p + 1;
#define PK(M) ((unsigned)__half_as_ushort(__float2half_rn(ldf(M, k0 * 60 + j, isf))) | \
               ((unsigned)__half_as_ushort(__float2half_rn(ldf(M, k1 * 60 + j, isf))) << 16))
      wsu[OFF_U1P + i] = PK(U1);
      wsu[OFF_W2P + i] = PK(W2);
      wsu[OFF_U2P + i] = PK(U2);
#undef PK
    }
    for (int i = t; i < 120; i += 256) {
      ws[OFF_B1 + i] = ldf(b1, i, isf);
      ws[OFF_B2 + i] = ldf(b2, i, isf);
    }
    for (int i = t; i < 300; i += 256) ws[OFF_WD + i] = ldf(Wd, i, isf);
    for (int i = t; i < 15;  i += 256) ws[OFF_BD + i] = ldf(bd, i, isf);
  }

  const int L = threadIdx.x & 63, q = L >> 4, c = L & 15;
  const int wid = blockIdx.x * 4 + (threadIdx.x >> 6);
  float* __restrict__ tab = ws + OFF_TAB;

  __shared__ int4 sB[64][8];
  if (threadIdx.x < 64) {
#pragma unroll
    for (int nt = 0; nt < 4; ++nt) {
      const int col = nt * 16 + c;
      sh8 B0, B1;
#pragma unroll
      for (int jj = 0; jj < 8; ++jj) {
        const int k0 = q * 8 + jj, k1 = 32 + q * 8 + jj;
        B0[jj] = (col < TABW) ? f2bf(ldf(W1, k0 * TABW + col, isf)) : (short)0;
        B1[jj] = (col < TABW && k1 < EMB_D)
                     ? f2bf(ldf(W1, k1 * TABW + col, isf)) : (short)0;
      }
      sB[L][nt * 2]     = *(const int4*)&B0;
      sB[L][nt * 2 + 1] = *(const int4*)&B1;
    }
  }
  float bi[4];
#pragma unroll
  for (int nt = 0; nt < 4; ++nt) {
    const int col = nt * 16 + c;
    bi[nt] = (col < TABW) ? ldf(b1, col, isf) : 0.f;
  }
  __syncthreads();

  for (int tile = wid; tile < NTILE; tile += BBLK * 4) {
    const int v0 = tile * 16;
    sh8 A0, A1;
#pragma unroll
    for (int jj = 0; jj < 8; ++jj) { A0[jj] = 0; A1[jj] = 0; }
    if (!isf) {
      const unsigned short* eb = (const unsigned short*)emb;
      const size_t rb = (size_t)(v0 + c) * EMB_D;
#pragma unroll
      for (int i = 0; i < 4; ++i) {
        unsigned d = *(const unsigned*)(eb + rb + q * 8 + 2 * i);
        A0[2 * i] = (short)(d & 0xffff); A0[2 * i + 1] = (short)(d >> 16);
      }
      const int k1b = 32 + q * 8;
#pragma unroll
      for (int i = 0; i < 4; ++i) {
        const int k = k1b + 2 * i;
        if (k + 1 < EMB_D) {
          unsigned d = *(const unsigned*)(eb + rb + k);
          A1[2 * i] = (short)(d & 0xffff); A1[2 * i + 1] = (short)(d >> 16);
        }
      }
    } else {
      const float* ef = (const float*)emb;
      const size_t rb = (size_t)(v0 + c) * EMB_D;
#pragma unroll
      for (int jj = 0; jj < 8; ++jj) {
        const int k0 = q * 8 + jj, k1 = 32 + q * 8 + jj;
        A0[jj] = f2bf(ef[rb + k0]);
        A1[jj] = (k1 < EMB_D) ? f2bf(ef[rb + k1]) : (short)0;
      }
    }
#pragma unroll
    for (int nt = 0; nt < 4; ++nt) {
      int4 b0i = sB[L][nt * 2], b1i = sB[L][nt * 2 + 1];
      sh8 B0 = *(const sh8*)&b0i, B1 = *(const sh8*)&b1i;
      const int col = nt * 16 + c;
      f4 acc = { bi[nt], bi[nt], bi[nt], bi[nt] };
      acc = __builtin_amdgcn_mfma_f32_16x16x32_bf16(A0, B0, acc, 0, 0, 0);
      acc = __builtin_amdgcn_mfma_f32_16x16x32_bf16(A1, B1, acc, 0, 0, 0);
      if (col < TABW) {
#pragma unroll
        for (int r = 0; r < 4; ++r)
          tab[(size_t)(v0 + q * 4 + r) * TABW + col] = acc[r];
      }
    }
  }
}

// ONE batch element per wave; 100-step GRU in inline asm (r17 lane map).
// ROUND-22: VALU-count surgery. Evidence r14-r21: wall tracks VALU instr
// count (r17 83/half=153us, r21 88/half=164us, r18 120/half=218us) with
// VALUBusy pinned 85-90% -> issue-throughput-bound. The readlane broadcast
// (20 readlane + 2 pack + 2 swizzle per half = 22 VALU) exists only to get
// h into SGPRs; but v_dot2 takes both operands in VGPRs. Replace with the
// LDS data path: 1 ds_write_b16 per layer (lane-mapped addr: lanes 0-19 ->
// bytes 2k, lanes 20-63 -> trash bytes 40.., exactly 2 lanes/bank = free)
// + 3 broadcast ds_read (same-addr = free). Pair layout in LDS dwords is
// bit-identical to v_pack_b32_f16 -> numerics unchanged. Kills the SGPR
// h double-buffers and readlane s_nops. 83 -> 62 VALU/half; DS 6 -> 12
// (r21 proved DS has headroom).
__global__ __launch_bounds__(256) void gru_main(
    const int* __restrict__ x, const float* __restrict__ ws,
    const void* __restrict__ emb, void* __restrict__ out)
{
  const int isf = detect_isf(emb);   // output dtype only
  const int j = threadIdx.x & 63;
  const int e = __builtin_amdgcn_readfirstlane(blockIdx.x * 4 + (threadIdx.x >> 6));
  const int jc = j < TABW ? j : 0;

  const int* xr = x + (size_t)e * SEQ_T;
  const float* tab = ws + OFF_TAB;
  const int o1 = jc * 40;                    // 10 packed dwords per column
  const int jc4 = jc * 4;                    // byte offset of col jc in tab row
  const int a1 = ((j - 20) & 63) * 4;        // bpermute addr: r -> h-lanes
  const int a2 = ((j + 40) & 63) * 4;        // bpermute addr: hc -> z-lanes
  const float br1 = ws[OFF_B1 + 60 + jc];
  const float bi2 = ws[OFF_B2 + jc];
  const float br2 = ws[OFF_B2 + 60 + jc];

  // per-wave LDS h-broadcast buffers: h1 at +0 (128B), h2 at +128 (128B).
  // write map: lane k<20 -> byte 2k (data dwords 0-9); lanes 20-63 ->
  // bytes 40..126 (trash dwords 10-31). 64 lanes over 32 dwords = 2/bank.
  __shared__ char sbuf[1024];
  const unsigned lb = (unsigned)(uintptr_t)&sbuf[0] + (threadIdx.x >> 6) * 256;
  const int wad = (int)(lb + (j < 20 ? 2 * j : 40 + 2 * (j - 20)));
  const int rad = (int)lb;
  float h2out;

  asm volatile(
    // ---- packed f16 weights: U1P v10-19, W2P v20-29, U2P v30-39 ----
    "global_load_dwordx4 v[10:13], %[o1], %[wsp] offset:0\n\t"
    "global_load_dwordx4 v[14:17], %[o1], %[wsp] offset:16\n\t"
    "global_load_dwordx2 v[18:19], %[o1], %[wsp] offset:32\n\t"
    "v_add_u32 v44, 0x960, %[o1]\n\t"
    "v_add_u32 v45, 0x12c0, %[o1]\n\t"
    "global_load_dwordx4 v[20:23], v44, %[wsp] offset:0\n\t"
    "global_load_dwordx4 v[24:27], v44, %[wsp] offset:16\n\t"
    "global_load_dwordx2 v[28:29], v44, %[wsp] offset:32\n\t"
    "global_load_dwordx4 v[30:33], v45, %[wsp] offset:0\n\t"
    "global_load_dwordx4 v[34:37], v45, %[wsp] offset:16\n\t"
    "global_load_dwordx2 v[38:39], v45, %[wsp] offset:32\n\t"
    // ---- h masters + h2 pair regs zero ----
    "v_mov_b32 v40, 0\n\t"
    "v_mov_b32 v41, 0\n\t"
    "v_mov_b32 v70, 0\n\tv_mov_b32 v71, 0\n\t"
    "v_mov_b32 v72, 0\n\tv_mov_b32 v73, 0\n\t"
    "v_mov_b32 v74, 0\n\tv_mov_b32 v75, 0\n\t"
    "v_mov_b32 v76, 0\n\tv_mov_b32 v77, 0\n\t"
    "v_mov_b32 v78, 0\n\tv_mov_b32 v79, 0\n\t"
    // ---- prime: mx0->v52, mx1->v42, mx2->v43; idx3->s65, idx4->s68 ----
    "s_load_dword s65, %[xp], 0x0\n\t"
    "s_load_dword s66, %[xp], 0x4\n\t"
    "s_load_dword s68, %[xp], 0x8\n\t"
    "s_waitcnt lgkmcnt(0)\n\t"
    "s_mul_i32 s65, s65, 240\n\t"
    "s_mul_i32 s66, s66, 240\n\t"
    "s_mul_i32 s68, s68, 240\n\t"
    "v_add_u32 v50, s65, %[jc4]\n\t"
    "global_load_dword v52, v50, %[tabp]\n\t"
    "v_add_u32 v50, s66, %[jc4]\n\t"
    "global_load_dword v42, v50, %[tabp]\n\t"
    "v_add_u32 v50, s68, %[jc4]\n\t"
    "global_load_dword v43, v50, %[tabp]\n\t"
    "s_load_dword s65, %[xp], 0xc\n\t"     // idx3 (odd stream)
    "s_load_dword s68, %[xp], 0x10\n\t"    // idx4 (even stream)
    "s_movk_i32 s64, 0x14\n\t"             // next odd x-offset (idx5)
    "s_movk_i32 s69, 0x18\n\t"             // next even x-offset (idx6)
    "s_movk_i32 s67, 0x32\n\t"             // 50 unrolled iterations
    "s_waitcnt vmcnt(2)\n\t"               // weights + mx0 ready
    // ======== PROLOGUE: L1(0)  (h1(-1)=0 -> mh = br1; mx0 = v52) ========
    "v_mov_b32 v44, %[br1]\n\t"
    "v_add_f32 v45, v52, v44\n\t"
    "v_mul_f32 v45, 0xbfb8aa3b, v45\n\t"
    "v_exp_f32 v45, v45\n\t"
    "s_nop 1\n\t"
    "v_add_f32 v45, 1.0, v45\n\t"
    "v_rcp_f32 v45, v45\n\t"
    "s_nop 1\n\t"
    "ds_bpermute_b32 v46, %[a1], v45\n\t"
    "s_waitcnt lgkmcnt(0)\n\t"
    "v_fma_f32 v47, v46, v44, v52\n\t"
    "v_mul_f32 v47, 0x4038aa3b, v47\n\t"
    "v_exp_f32 v47, v47\n\t"
    "s_nop 1\n\t"
    "v_add_f32 v47, 1.0, v47\n\t"
    "v_rcp_f32 v47, v47\n\t"
    "s_nop 1\n\t"
    "v_fma_f32 v47, -2.0, v47, 1.0\n\t"
    "ds_bpermute_b32 v46, %[a2], v47\n\t"
    "s_waitcnt lgkmcnt(0)\n\t"
    "v_sub_f32 v48, v40, v46\n\t"
    "v_fma_f32 v40, v45, v48, v46\n\t"     // h1(0)
    "v_cvt_f16_f32 v46, v40\n\t"
    "ds_write_b16 %[wad], v46\n\t"
    "ds_read_b128 v[60:63], %[rad]\n\t"
    "ds_read_b128 v[64:67], %[rad] offset:16\n\t"
    "ds_read_b64  v[68:69], %[rad] offset:32\n\t"
    // ======== LOOP k=0..49 ========
    "0:\n\t"
    // ---- HALF A: L2(2k) || L1(2k+1). h1(2k)=v60-69, h2(2k-1)=v70-79.
    "v_mov_b32 v44, %[br1]\n\t"
    "v_mov_b32 v51, %[bi2]\n\t"
    "v_mov_b32 v52, %[br2]\n\t"
    "s_waitcnt lgkmcnt(0)\n\t"             // h pair reads (+s_load) done
    "v_dot2_f32_f16 v44, v60, v10, v44\n\t"
    "v_dot2_f32_f16 v51, v60, v20, v51\n\t"
    "v_dot2_f32_f16 v52, v70, v30, v52\n\t"
    "v_dot2_f32_f16 v44, v61, v11, v44\n\t"
    "v_dot2_f32_f16 v51, v61, v21, v51\n\t"
    "v_dot2_f32_f16 v52, v71, v31, v52\n\t"
    "v_dot2_f32_f16 v44, v62, v12, v44\n\t"
    "v_dot2_f32_f16 v51, v62, v22, v51\n\t"
    "v_dot2_f32_f16 v52, v72, v32, v52\n\t"
    "v_dot2_f32_f16 v44, v63, v13, v44\n\t"
    "v_dot2_f32_f16 v51, v63, v23, v51\n\t"
    "v_dot2_f32_f16 v52, v73, v33, v52\n\t"
    "v_dot2_f32_f16 v44, v64, v14, v44\n\t"
    "v_dot2_f32_f16 v51, v64, v24, v51\n\t"
    "v_dot2_f32_f16 v52, v74, v34, v52\n\t"
    "v_dot2_f32_f16 v44, v65, v15, v44\n\t"
    "v_dot2_f32_f16 v51, v65, v25, v51\n\t"
    "v_dot2_f32_f16 v52, v75, v35, v52\n\t"
    "v_dot2_f32_f16 v44, v66, v16, v44\n\t"
    "v_dot2_f32_f16 v51, v66, v26, v51\n\t"
    "v_dot2_f32_f16 v52, v76, v36, v52\n\t"
    "v_dot2_f32_f16 v44, v67, v17, v44\n\t"
    "v_dot2_f32_f16 v51, v67, v27, v51\n\t"
    "v_dot2_f32_f16 v52, v77, v37, v52\n\t"
    "v_dot2_f32_f16 v44, v68, v18, v44\n\t"
    "v_dot2_f32_f16 v51, v68, v28, v51\n\t"
    "v_dot2_f32_f16 v52, v78, v38, v52\n\t"
    "v_dot2_f32_f16 v44, v69, v19, v44\n\t"
    "v_dot2_f32_f16 v51, v69, v29, v51\n\t"
    "v_dot2_f32_f16 v52, v79, v39, v52\n\t"
    "s_waitcnt vmcnt(1)\n\t"               // mx(2k+1) in v42
    "v_add_f32 v45, v42, v44\n\t"
    "v_add_f32 v53, v51, v52\n\t"
    "v_mul_f32 v45, 0xbfb8aa3b, v45\n\t"
    "v_mul_f32 v53, 0xbfb8aa3b, v53\n\t"
    "v_exp_f32 v45, v45\n\t"
    "v_exp_f32 v53, v53\n\t"
    "v_add_f32 v45, 1.0, v45\n\t"
    "v_add_f32 v53, 1.0, v53\n\t"
    "v_rcp_f32 v45, v45\n\t"
    "v_rcp_f32 v53, v53\n\t"
    "ds_bpermute_b32 v46, %[a1], v45\n\t"
    "ds_bpermute_b32 v54, %[a1], v53\n\t"
    "s_mul_i32 s66, s65, 240\n\t"
    "v_add_u32 v50, s66, %[jc4]\n\t"
    "s_waitcnt lgkmcnt(0)\n\t"
    "v_fma_f32 v47, v46, v44, v42\n\t"     // hp1, last v42 use
    "v_fma_f32 v55, v54, v52, v51\n\t"     // hp2
    "global_load_dword v42, v50, %[tabp]\n\t"  // mx(2k+3)
    "s_min_u32 s64, s64, 396\n\t"
    "s_load_dword s65, %[xp], s64\n\t"     // idx(2k+5)
    "s_add_u32 s64, s64, 8\n\t"
    "v_mul_f32 v47, 0x4038aa3b, v47\n\t"
    "v_mul_f32 v55, 0x4038aa3b, v55\n\t"
    "v_exp_f32 v47, v47\n\t"
    "v_exp_f32 v55, v55\n\t"
    "v_add_f32 v47, 1.0, v47\n\t"
    "v_add_f32 v55, 1.0, v55\n\t"
    "v_rcp_f32 v47, v47\n\t"
    "v_rcp_f32 v55, v55\n\t"
    "s_nop 0\n\t"
    "v_fma_f32 v47, -2.0, v47, 1.0\n\t"    // hc1
    "v_fma_f32 v55, -2.0, v55, 1.0\n\t"    // hc2
    "ds_bpermute_b32 v46, %[a2], v47\n\t"
    "ds_bpermute_b32 v54, %[a2], v55\n\t"
    "s_waitcnt lgkmcnt(0)\n\t"
    "v_sub_f32 v48, v40, v46\n\t"
    "v_fma_f32 v40, v45, v48, v46\n\t"     // h1(2k+1)
    "v_sub_f32 v48, v41, v54\n\t"
    "v_fma_f32 v41, v53, v48, v54\n\t"     // h2(2k)
    "v_cvt_f16_f32 v46, v40\n\t"
    "v_cvt_f16_f32 v54, v41\n\t"
    "ds_write_b16 %[wad], v46\n\t"
    "ds_write_b16 %[wad], v54 offset:128\n\t"
    "ds_read_b128 v[60:63], %[rad]\n\t"
    "ds_read_b128 v[64:67], %[rad] offset:16\n\t"
    "ds_read_b64  v[68:69], %[rad] offset:32\n\t"
    "ds_read_b128 v[70:73], %[rad] offset:128\n\t"
    "ds_read_b128 v[74:77], %[rad] offset:144\n\t"
    "ds_read_b64  v[78:79], %[rad] offset:160\n\t"
    // ---- HALF B: L2(2k+1) || L1(2k+2). h1(2k+1)=v60-69, h2(2k)=v70-79.
    "v_mov_b32 v44, %[br1]\n\t"
    "v_mov_b32 v51, %[bi2]\n\t"
    "v_mov_b32 v52, %[br2]\n\t"
    "s_waitcnt lgkmcnt(0)\n\t"
    "v_dot2_f32_f16 v44, v60, v10, v44\n\t"
    "v_dot2_f32_f16 v51, v60, v20, v51\n\t"
    "v_dot2_f32_f16 v52, v70, v30, v52\n\t"
    "v_dot2_f32_f16 v44, v61, v11, v44\n\t"
    "v_dot2_f32_f16 v51, v61, v21, v51\n\t"
    "v_dot2_f32_f16 v52, v71, v31, v52\n\t"
    "v_dot2_f32_f16 v44, v62, v12, v44\n\t"
    "v_dot2_f32_f16 v51, v62, v22, v51\n\t"
    "v_dot2_f32_f16 v52, v72, v32, v52\n\t"
    "v_dot2_f32_f16 v44, v63, v13, v44\n\t"
    "v_dot2_f32_f16 v51, v63, v23, v51\n\t"
    "v_dot2_f32_f16 v52, v73, v33, v52\n\t"
    "v_dot2_f32_f16 v44, v64, v14, v44\n\t"
    "v_dot2_f32_f16 v51, v64, v24, v51\n\t"
    "v_dot2_f32_f16 v52, v74, v34, v52\n\t"
    "v_dot2_f32_f16 v44, v65, v15, v44\n\t"
    "v_dot2_f32_f16 v51, v65, v25, v51\n\t"
    "v_dot2_f32_f16 v52, v75, v35, v52\n\t"
    "v_dot2_f32_f16 v44, v66, v16, v44\n\t"
    "v_dot2_f32_f16 v51, v66, v26, v51\n\t"
    "v_dot2_f32_f16 v52, v76, v36, v52\n\t"
    "v_dot2_f32_f16 v44, v67, v17, v44\n\t"
    "v_dot2_f32_f16 v51, v67, v27, v51\n\t"
    "v_dot2_f32_f16 v52, v77, v37, v52\n\t"
    "v_dot2_f32_f16 v44, v68, v18, v44\n\t"
    "v_dot2_f32_f16 v51, v68, v28, v51\n\t"
    "v_dot2_f32_f16 v52, v78, v38, v52\n\t"
    "v_dot2_f32_f16 v44, v69, v19, v44\n\t"
    "v_dot2_f32_f16 v51, v69, v29, v51\n\t"
    "v_dot2_f32_f16 v52, v79, v39, v52\n\t"
    "s_waitcnt vmcnt(1)\n\t"               // mx(2k+2) in v43
    "v_add_f32 v45, v43, v44\n\t"
    "v_add_f32 v53, v51, v52\n\t"
    "v_mul_f32 v45, 0xbfb8aa3b, v45\n\t"
    "v_mul_f32 v53, 0xbfb8aa3b, v53\n\t"
    "v_exp_f32 v45, v45\n\t"
    "v_exp_f32 v53, v53\n\t"
    "v_add_f32 v45, 1.0, v45\n\t"
    "v_add_f32 v53, 1.0, v53\n\t"
    "v_rcp_f32 v45, v45\n\t"
    "v_rcp_f32 v53, v53\n\t"
    "ds_bpermute_b32 v46, %[a1], v45\n\t"
    "ds_bpermute_b32 v54, %[a1], v53\n\t"
    "s_mul_i32 s66, s68, 240\n\t"
    "v_add_u32 v50, s66, %[jc4]\n\t"
    "s_waitcnt lgkmcnt(0)\n\t"
    "v_fma_f32 v47, v46, v44, v43\n\t"     // hp1, last v43 use
    "v_fma_f32 v55, v54, v52, v51\n\t"     // hp2
    "global_load_dword v43, v50, %[tabp]\n\t"  // mx(2k+4)
    "s_min_u32 s69, s69, 392\n\t"
    "s_load_dword s68, %[xp], s69\n\t"     // idx(2k+6)
    "s_add_u32 s69, s69, 8\n\t"
    "v_mul_f32 v47, 0x4038aa3b, v47\n\t"
    "v_mul_f32 v55, 0x4038aa3b, v55\n\t"
    "v_exp_f32 v47, v47\n\t"
    "v_exp_f32 v55, v55\n\t"
    "v_add_f32 v47, 1.0, v47\n\t"
    "v_add_f32 v55, 1.0, v55\n\t"
    "v_rcp_f32 v47, v47\n\t"
    "v_rcp_f32 v55, v55\n\t"
    "s_nop 0\n\t"
    "v_fma_f32 v47, -2.0, v47, 1.0\n\t"
    "v_fma_f32 v55, -2.0, v55, 1.0\n\t"
    "ds_bpermute_b32 v46, %[a2], v47\n\t"
    "ds_bpermute_b32 v54, %[a2], v55\n\t"
    "s_waitcnt lgkmcnt(0)\n\t"
    "v_sub_f32 v48, v40, v46\n\t"
    "v_fma_f32 v40, v45, v48, v46\n\t"     // h1(2k+2)
    "v_sub_f32 v48, v41, v54\n\t"
    "v_fma_f32 v41, v53, v48, v54\n\t"     // h2(2k+1)
    "v_cvt_f16_f32 v46, v40\n\t"
    "v_cvt_f16_f32 v54, v41\n\t"
    "ds_write_b16 %[wad], v46\n\t"
    "ds_write_b16 %[wad], v54 offset:128\n\t"
    "ds_read_b128 v[60:63], %[rad]\n\t"
    "ds_read_b128 v[64:67], %[rad] offset:16\n\t"
    "ds_read_b64  v[68:69], %[rad] offset:32\n\t"
    "ds_read_b128 v[70:73], %[rad] offset:128\n\t"
    "ds_read_b128 v[74:77], %[rad] offset:144\n\t"
    "ds_read_b64  v[78:79], %[rad] offset:160\n\t"
    "s_sub_u32 s67, s67, 1\n\t"
    "s_cmp_lg_u32 s67, 0\n\t"
    "s_cbranch_scc1 0b\n\t"
    "s_waitcnt vmcnt(0) lgkmcnt(0)\n\t"
    "v_mov_b32 %[h2o], v41\n\t"
    : [h2o] "=v"(h2out)
    : [wsp] "s"(ws), [xp] "s"(xr), [tabp] "s"(tab),
      [o1] "v"(o1), [jc4] "v"(jc4), [a1] "v"(a1), [a2] "v"(a2),
      [br1] "v"(br1), [bi2] "v"(bi2), [br2] "v"(br2),
      [wad] "v"(wad), [rad] "v"(rad)
    : "memory", "vcc", "scc",
      "v10","v11","v12","v13","v14","v15","v16","v17","v18","v19",
      "v20","v21","v22","v23","v24","v25","v26","v27","v28","v29",
      "v30","v31","v32","v33","v34","v35","v36","v37","v38","v39",
      "v40","v41","v42","v43","v44","v45","v46","v47","v48","v50",
      "v51","v52","v53","v54","v55",
      "v60","v61","v62","v63","v64","v65","v66","v67","v68","v69",
      "v70","v71","v72","v73","v74","v75","v76","v77","v78","v79",
      "s64","s65","s66","s67","s68","s69");

  // ---- dense: logits = h2 @ Wd + bd (h2 master fp32 in lanes 0..19) ----
  if (j < 15) {
    float a = ws[OFF_BD + j];
#pragma unroll
    for (int k = 0; k < HID; ++k)
      a = fmaf(rdl(h2out, k), ws[OFF_WD + k * 15 + j], a);
    if (isf) ((float*)out)[(size_t)e * 15 + j] = a;
    else ((__hip_bfloat16*)out)[(size_t)e * 15 + j] = __float2bfloat16(a);
  }
}

extern "C" void kernel_launch(void* const* d_in, const int* in_sizes, int n_in,
                              void* d_out, int out_size, void* d_ws, size_t ws_size,
                              hipStream_t stream) {
  const int* x    = (const int*)d_in[0];
  const void* emb = d_in[1];
  const void* W1  = d_in[2];
  const void* U1  = d_in[3];
  const void* b1  = d_in[4];
  const void* W2  = d_in[5];
  const void* U2  = d_in[6];
  const void* b2  = d_in[7];
  const void* Wd  = d_in[8];
  const void* bd  = d_in[9];
  float* ws = (float*)d_ws;   // 12,016,640 B used (proven safe)

  build_table<<<BBLK, 256, 0, stream>>>(
      emb, W1, b1, U1, W2, U2, b2, Wd, bd, ws);
  gru_main<<<2048, 256, 0, stream>>>(x, ws, emb, d_out);
}

// Round 9
// 200.272 us; speedup vs baseline: 1.4484x; 1.0125x over previous
//
#include <hip/hip_runtime.h>
#include <hip/hip_bf16.h>
#include <hip/hip_fp16.h>

#define SEQ_T 100
#define HID 20
#define EMB_D 50
#define VOCAB_N 50000
#define TABW 60          // tab row stride (floats) = 60 gate cols [z20|r20|h20]
#define NTILE 3125       // VOCAB_N/16
#define BBLK 782         // build_table blocks (x4 waves = 3128 waves, 1 tile/wave)

typedef short sh8 __attribute__((ext_vector_type(8)));   // 8 bf16 bit patterns
typedef float f4  __attribute__((ext_vector_type(4)));

// ws layout (float/dword offsets). TOTAL footprint unchanged: 12,016,640 B.
#define OFF_U1P 0        // 600 dwords (60 cols x 10 packed f16 k-pairs)
#define OFF_W2P 600
#define OFF_U2P 1200
#define OFF_B1  3600     // 120 fp32
#define OFF_B2  3720     // 120 fp32
#define OFF_WD  3840     // 300 fp32
#define OFF_BD  4140     // 15 fp32
#define OFF_TAB 4160     // 50000*60 fp32

__device__ __forceinline__ float ldf(const void* p, int i, int isf) {
  return isf ? ((const float*)p)[i]
             : __bfloat162float(((const __hip_bfloat16*)p)[i]);
}
__device__ __forceinline__ short f2bf(float f) {   // RNE fp32->bf16 bits
  unsigned u = __float_as_uint(f);
  u += 0x7fffu + ((u >> 16) & 1u);
  return (short)(u >> 16);
}
__device__ __forceinline__ float rdl(float v, int l) {
  return __uint_as_float(__builtin_amdgcn_readlane(__float_as_uint(v), l));
}
__device__ __forceinline__ int detect_isf(const void* emb) {
  uint4 dv = ((const uint4*)emb)[threadIdx.x & 63];
  int big = 0;
#pragma unroll
  for (int i = 0; i < 4; ++i) {
    unsigned w = ((const unsigned*)&dv)[i];
    big |= (((w >> 7) & 0xFF) >= 140) | (((w >> 23) & 0xFF) >= 140);
  }
  return (__ballot(big) != 0ull) ? 1 : 0;
}

// tab = emb @ W1 + bi1 on the matrix cores (round-13 structure, verified).
__global__ __launch_bounds__(256) void build_table(
    const void* __restrict__ emb, const void* __restrict__ W1,
    const void* __restrict__ b1,
    const void* __restrict__ U1, const void* __restrict__ W2,
    const void* __restrict__ U2, const void* __restrict__ b2,
    const void* __restrict__ Wd, const void* __restrict__ bd,
    float* __restrict__ ws)
{
  const int isf = detect_isf(emb);
  if (blockIdx.x == 0) {                     // fold: weight prep
    const int t = threadIdx.x;
    unsigned* wsu = (unsigned*)ws;
    for (int i = t; i < 600; i += 256) {
      const int j = i / 10, p = i % 10;
      const int k0 = 2 * p, k1 = 2 * p + 1;
#define PK(M) ((unsigned)__half_as_ushort(__float2half_rn(ldf(M, k0 * 60 + j, isf))) | \
               ((unsigned)__half_as_ushort(__float2half_rn(ldf(M, k1 * 60 + j, isf))) << 16))
      wsu[OFF_U1P + i] = PK(U1);
      wsu[OFF_W2P + i] = PK(W2);
      wsu[OFF_U2P + i] = PK(U2);
#undef PK
    }
    for (int i = t; i < 120; i += 256) {
      ws[OFF_B1 + i] = ldf(b1, i, isf);
      ws[OFF_B2 + i] = ldf(b2, i, isf);
    }
    for (int i = t; i < 300; i += 256) ws[OFF_WD + i] = ldf(Wd, i, isf);
    for (int i = t; i < 15;  i += 256) ws[OFF_BD + i] = ldf(bd, i, isf);
  }

  const int L = threadIdx.x & 63, q = L >> 4, c = L & 15;
  const int wid = blockIdx.x * 4 + (threadIdx.x >> 6);
  float* __restrict__ tab = ws + OFF_TAB;

  __shared__ int4 sB[64][8];
  if (threadIdx.x < 64) {
#pragma unroll
    for (int nt = 0; nt < 4; ++nt) {
      const int col = nt * 16 + c;
      sh8 B0, B1;
#pragma unroll
      for (int jj = 0; jj < 8; ++jj) {
        const int k0 = q * 8 + jj, k1 = 32 + q * 8 + jj;
        B0[jj] = (col < TABW) ? f2bf(ldf(W1, k0 * TABW + col, isf)) : (short)0;
        B1[jj] = (col < TABW && k1 < EMB_D)
                     ? f2bf(ldf(W1, k1 * TABW + col, isf)) : (short)0;
      }
      sB[L][nt * 2]     = *(const int4*)&B0;
      sB[L][nt * 2 + 1] = *(const int4*)&B1;
    }
  }
  float bi[4];
#pragma unroll
  for (int nt = 0; nt < 4; ++nt) {
    const int col = nt * 16 + c;
    bi[nt] = (col < TABW) ? ldf(b1, col, isf) : 0.f;
  }
  __syncthreads();

  for (int tile = wid; tile < NTILE; tile += BBLK * 4) {
    const int v0 = tile * 16;
    sh8 A0, A1;
#pragma unroll
    for (int jj = 0; jj < 8; ++jj) { A0[jj] = 0; A1[jj] = 0; }
    if (!isf) {
      const unsigned short* eb = (const unsigned short*)emb;
      const size_t rb = (size_t)(v0 + c) * EMB_D;
#pragma unroll
      for (int i = 0; i < 4; ++i) {
        unsigned d = *(const unsigned*)(eb + rb + q * 8 + 2 * i);
        A0[2 * i] = (short)(d & 0xffff); A0[2 * i + 1] = (short)(d >> 16);
      }
      const int k1b = 32 + q * 8;
#pragma unroll
      for (int i = 0; i < 4; ++i) {
        const int k = k1b + 2 * i;
        if (k + 1 < EMB_D) {
          unsigned d = *(const unsigned*)(eb + rb + k);
          A1[2 * i] = (short)(d & 0xffff); A1[2 * i + 1] = (short)(d >> 16);
        }
      }
    } else {
      const float* ef = (const float*)emb;
      const size_t rb = (size_t)(v0 + c) * EMB_D;
#pragma unroll
      for (int jj = 0; jj < 8; ++jj) {
        const int k0 = q * 8 + jj, k1 = 32 + q * 8 + jj;
        A0[jj] = f2bf(ef[rb + k0]);
        A1[jj] = (k1 < EMB_D) ? f2bf(ef[rb + k1]) : (short)0;
      }
    }
#pragma unroll
    for (int nt = 0; nt < 4; ++nt) {
      int4 b0i = sB[L][nt * 2], b1i = sB[L][nt * 2 + 1];
      sh8 B0 = *(const sh8*)&b0i, B1 = *(const sh8*)&b1i;
      const int col = nt * 16 + c;
      f4 acc = { bi[nt], bi[nt], bi[nt], bi[nt] };
      acc = __builtin_amdgcn_mfma_f32_16x16x32_bf16(A0, B0, acc, 0, 0, 0);
      acc = __builtin_amdgcn_mfma_f32_16x16x32_bf16(A1, B1, acc, 0, 0, 0);
      if (col < TABW) {
#pragma unroll
        for (int r = 0; r < 4; ++r)
          tab[(size_t)(v0 + q * 4 + r) * TABW + col] = acc[r];
      }
    }
  }
}

// ONE batch element per wave; 100-step GRU in inline asm (r22 structure).
// ROUND-23: occupancy surgery. r22 analysis: per-SIMD VALU issue only ~33%
// (CU VALUBusy 82% = 1-0.67^4); wall is 2/3 latency stalls at ~4 blocks/CU.
// Cause: asm clobbered v10-79 and compiler allocated its own values ABOVE
// v79 -> ~128 VGPR -> 4 waves/SIMD. Fix: (1) repack h-pair regs to v56-75
// (explicit top v75, contiguous) and __launch_bounds__(256,6) -> cap 85
// VGPR -> 6 waves/SIMD (+50% TLP to cover the ds/bpermute/TRANS stalls).
// (2) bias chain-init via dot src2 (first v_dot2 reads bias VGPR as C) --
// removes 3 v_mov/half, bit-identical.
__global__ __launch_bounds__(256, 6) void gru_main(
    const int* __restrict__ x, const float* __restrict__ ws,
    const void* __restrict__ emb, void* __restrict__ out)
{
  const int isf = detect_isf(emb);   // output dtype only
  const int j = threadIdx.x & 63;
  const int e = __builtin_amdgcn_readfirstlane(blockIdx.x * 4 + (threadIdx.x >> 6));
  const int jc = j < TABW ? j : 0;

  const int* xr = x + (size_t)e * SEQ_T;
  const float* tab = ws + OFF_TAB;
  const int o1 = jc * 40;                    // 10 packed dwords per column
  const int jc4 = jc * 4;                    // byte offset of col jc in tab row
  const int a1 = ((j - 20) & 63) * 4;        // bpermute addr: r -> h-lanes
  const int a2 = ((j + 40) & 63) * 4;        // bpermute addr: hc -> z-lanes
  const float br1 = ws[OFF_B1 + 60 + jc];
  const float bi2 = ws[OFF_B2 + jc];
  const float br2 = ws[OFF_B2 + 60 + jc];

  // per-wave LDS h-broadcast buffers: h1 at +0 (128B), h2 at +128 (128B).
  // write map: lane k<20 -> byte 2k (data dwords 0-9); lanes 20-63 ->
  // bytes 40..126 (trash dwords 10-31). 64 lanes over 32 dwords = 2/bank.
  __shared__ char sbuf[1024];
  const unsigned lb = (unsigned)(uintptr_t)&sbuf[0] + (threadIdx.x >> 6) * 256;
  const int wad = (int)(lb + (j < 20 ? 2 * j : 40 + 2 * (j - 20)));
  const int rad = (int)lb;
  float h2out;

  asm volatile(
    // ---- packed f16 weights: U1P v10-19, W2P v20-29, U2P v30-39 ----
    "global_load_dwordx4 v[10:13], %[o1], %[wsp] offset:0\n\t"
    "global_load_dwordx4 v[14:17], %[o1], %[wsp] offset:16\n\t"
    "global_load_dwordx2 v[18:19], %[o1], %[wsp] offset:32\n\t"
    "v_add_u32 v44, 0x960, %[o1]\n\t"
    "v_add_u32 v45, 0x12c0, %[o1]\n\t"
    "global_load_dwordx4 v[20:23], v44, %[wsp] offset:0\n\t"
    "global_load_dwordx4 v[24:27], v44, %[wsp] offset:16\n\t"
    "global_load_dwordx2 v[28:29], v44, %[wsp] offset:32\n\t"
    "global_load_dwordx4 v[30:33], v45, %[wsp] offset:0\n\t"
    "global_load_dwordx4 v[34:37], v45, %[wsp] offset:16\n\t"
    "global_load_dwordx2 v[38:39], v45, %[wsp] offset:32\n\t"
    // ---- h masters + h2 pair regs zero ----
    "v_mov_b32 v40, 0\n\t"
    "v_mov_b32 v41, 0\n\t"
    "v_mov_b32 v66, 0\n\tv_mov_b32 v67, 0\n\t"
    "v_mov_b32 v68, 0\n\tv_mov_b32 v69, 0\n\t"
    "v_mov_b32 v70, 0\n\tv_mov_b32 v71, 0\n\t"
    "v_mov_b32 v72, 0\n\tv_mov_b32 v73, 0\n\t"
    "v_mov_b32 v74, 0\n\tv_mov_b32 v75, 0\n\t"
    // ---- prime: mx0->v52, mx1->v42, mx2->v43; idx3->s65, idx4->s68 ----
    "s_load_dword s65, %[xp], 0x0\n\t"
    "s_load_dword s66, %[xp], 0x4\n\t"
    "s_load_dword s68, %[xp], 0x8\n\t"
    "s_waitcnt lgkmcnt(0)\n\t"
    "s_mul_i32 s65, s65, 240\n\t"
    "s_mul_i32 s66, s66, 240\n\t"
    "s_mul_i32 s68, s68, 240\n\t"
    "v_add_u32 v50, s65, %[jc4]\n\t"
    "global_load_dword v52, v50, %[tabp]\n\t"
    "v_add_u32 v50, s66, %[jc4]\n\t"
    "global_load_dword v42, v50, %[tabp]\n\t"
    "v_add_u32 v50, s68, %[jc4]\n\t"
    "global_load_dword v43, v50, %[tabp]\n\t"
    "s_load_dword s65, %[xp], 0xc\n\t"     // idx3 (odd stream)
    "s_load_dword s68, %[xp], 0x10\n\t"    // idx4 (even stream)
    "s_movk_i32 s64, 0x14\n\t"             // next odd x-offset (idx5)
    "s_movk_i32 s69, 0x18\n\t"             // next even x-offset (idx6)
    "s_movk_i32 s67, 0x32\n\t"             // 50 unrolled iterations
    "s_waitcnt vmcnt(2)\n\t"               // weights + mx0 ready
    // ======== PROLOGUE: L1(0)  (h1(-1)=0 -> mh = br1; mx0 = v52) ========
    "v_mov_b32 v44, %[br1]\n\t"
    "v_add_f32 v45, v52, v44\n\t"
    "v_mul_f32 v45, 0xbfb8aa3b, v45\n\t"
    "v_exp_f32 v45, v45\n\t"
    "s_nop 1\n\t"
    "v_add_f32 v45, 1.0, v45\n\t"
    "v_rcp_f32 v45, v45\n\t"
    "s_nop 1\n\t"
    "ds_bpermute_b32 v46, %[a1], v45\n\t"
    "s_waitcnt lgkmcnt(0)\n\t"
    "v_fma_f32 v47, v46, v44, v52\n\t"
    "v_mul_f32 v47, 0x4038aa3b, v47\n\t"
    "v_exp_f32 v47, v47\n\t"
    "s_nop 1\n\t"
    "v_add_f32 v47, 1.0, v47\n\t"
    "v_rcp_f32 v47, v47\n\t"
    "s_nop 1\n\t"
    "v_fma_f32 v47, -2.0, v47, 1.0\n\t"
    "ds_bpermute_b32 v46, %[a2], v47\n\t"
    "s_waitcnt lgkmcnt(0)\n\t"
    "v_sub_f32 v48, v40, v46\n\t"
    "v_fma_f32 v40, v45, v48, v46\n\t"     // h1(0)
    "v_cvt_f16_f32 v46, v40\n\t"
    "ds_write_b16 %[wad], v46\n\t"
    "ds_read_b128 v[56:59], %[rad]\n\t"
    "ds_read_b128 v[60:63], %[rad] offset:16\n\t"
    "ds_read_b64  v[64:65], %[rad] offset:32\n\t"
    // ======== LOOP k=0..49 ========
    "0:\n\t"
    // ---- HALF A: L2(2k) || L1(2k+1). h1(2k)=v56-65, h2(2k-1)=v66-75.
    "s_waitcnt lgkmcnt(0)\n\t"             // h pair reads (+s_load) done
    "v_dot2_f32_f16 v44, v56, v10, %[br1]\n\t"
    "v_dot2_f32_f16 v51, v56, v20, %[bi2]\n\t"
    "v_dot2_f32_f16 v52, v66, v30, %[br2]\n\t"
    "v_dot2_f32_f16 v44, v57, v11, v44\n\t"
    "v_dot2_f32_f16 v51, v57, v21, v51\n\t"
    "v_dot2_f32_f16 v52, v67, v31, v52\n\t"
    "v_dot2_f32_f16 v44, v58, v12, v44\n\t"
    "v_dot2_f32_f16 v51, v58, v22, v51\n\t"
    "v_dot2_f32_f16 v52, v68, v32, v52\n\t"
    "v_dot2_f32_f16 v44, v59, v13, v44\n\t"
    "v_dot2_f32_f16 v51, v59, v23, v51\n\t"
    "v_dot2_f32_f16 v52, v69, v33, v52\n\t"
    "v_dot2_f32_f16 v44, v60, v14, v44\n\t"
    "v_dot2_f32_f16 v51, v60, v24, v51\n\t"
    "v_dot2_f32_f16 v52, v70, v34, v52\n\t"
    "v_dot2_f32_f16 v44, v61, v15, v44\n\t"
    "v_dot2_f32_f16 v51, v61, v25, v51\n\t"
    "v_dot2_f32_f16 v52, v71, v35, v52\n\t"
    "v_dot2_f32_f16 v44, v62, v16, v44\n\t"
    "v_dot2_f32_f16 v51, v62, v26, v51\n\t"
    "v_dot2_f32_f16 v52, v72, v36, v52\n\t"
    "v_dot2_f32_f16 v44, v63, v17, v44\n\t"
    "v_dot2_f32_f16 v51, v63, v27, v51\n\t"
    "v_dot2_f32_f16 v52, v73, v37, v52\n\t"
    "v_dot2_f32_f16 v44, v64, v18, v44\n\t"
    "v_dot2_f32_f16 v51, v64, v28, v51\n\t"
    "v_dot2_f32_f16 v52, v74, v38, v52\n\t"
    "v_dot2_f32_f16 v44, v65, v19, v44\n\t"
    "v_dot2_f32_f16 v51, v65, v29, v51\n\t"
    "v_dot2_f32_f16 v52, v75, v39, v52\n\t"
    "s_waitcnt vmcnt(1)\n\t"               // mx(2k+1) in v42
    "v_add_f32 v45, v42, v44\n\t"
    "v_add_f32 v53, v51, v52\n\t"
    "v_mul_f32 v45, 0xbfb8aa3b, v45\n\t"
    "v_mul_f32 v53, 0xbfb8aa3b, v53\n\t"
    "v_exp_f32 v45, v45\n\t"
    "v_exp_f32 v53, v53\n\t"
    "v_add_f32 v45, 1.0, v45\n\t"
    "v_add_f32 v53, 1.0, v53\n\t"
    "v_rcp_f32 v45, v45\n\t"
    "v_rcp_f32 v53, v53\n\t"
    "ds_bpermute_b32 v46, %[a1], v45\n\t"
    "ds_bpermute_b32 v54, %[a1], v53\n\t"
    "s_mul_i32 s66, s65, 240\n\t"
    "v_add_u32 v50, s66, %[jc4]\n\t"
    "s_waitcnt lgkmcnt(0)\n\t"
    "v_fma_f32 v47, v46, v44, v42\n\t"     // hp1, last v42 use
    "v_fma_f32 v55, v54, v52, v51\n\t"     // hp2
    "global_load_dword v42, v50, %[tabp]\n\t"  // mx(2k+3)
    "s_min_u32 s64, s64, 396\n\t"
    "s_load_dword s65, %[xp], s64\n\t"     // idx(2k+5)
    "s_add_u32 s64, s64, 8\n\t"
    "v_mul_f32 v47, 0x4038aa3b, v47\n\t"
    "v_mul_f32 v55, 0x4038aa3b, v55\n\t"
    "v_exp_f32 v47, v47\n\t"
    "v_exp_f32 v55, v55\n\t"
    "v_add_f32 v47, 1.0, v47\n\t"
    "v_add_f32 v55, 1.0, v55\n\t"
    "v_rcp_f32 v47, v47\n\t"
    "v_rcp_f32 v55, v55\n\t"
    "s_nop 0\n\t"
    "v_fma_f32 v47, -2.0, v47, 1.0\n\t"    // hc1
    "v_fma_f32 v55, -2.0, v55, 1.0\n\t"    // hc2
    "ds_bpermute_b32 v46, %[a2], v47\n\t"
    "ds_bpermute_b32 v54, %[a2], v55\n\t"
    "s_waitcnt lgkmcnt(0)\n\t"
    "v_sub_f32 v48, v40, v46\n\t"
    "v_fma_f32 v40, v45, v48, v46\n\t"     // h1(2k+1)
    "v_sub_f32 v48, v41, v54\n\t"
    "v_fma_f32 v41, v53, v48, v54\n\t"     // h2(2k)
    "v_cvt_f16_f32 v46, v40\n\t"
    "v_cvt_f16_f32 v54, v41\n\t"
    "ds_write_b16 %[wad], v46\n\t"
    "ds_write_b16 %[wad], v54 offset:128\n\t"
    "ds_read_b128 v[56:59], %[rad]\n\t"
    "ds_read_b128 v[60:63], %[rad] offset:16\n\t"
    "ds_read_b64  v[64:65], %[rad] offset:32\n\t"
    "ds_read_b128 v[66:69], %[rad] offset:128\n\t"
    "ds_read_b128 v[70:73], %[rad] offset:144\n\t"
    "ds_read_b64  v[74:75], %[rad] offset:160\n\t"
    // ---- HALF B: L2(2k+1) || L1(2k+2). h1(2k+1)=v56-65, h2(2k)=v66-75.
    "s_waitcnt lgkmcnt(0)\n\t"
    "v_dot2_f32_f16 v44, v56, v10, %[br1]\n\t"
    "v_dot2_f32_f16 v51, v56, v20, %[bi2]\n\t"
    "v_dot2_f32_f16 v52, v66, v30, %[br2]\n\t"
    "v_dot2_f32_f16 v44, v57, v11, v44\n\t"
    "v_dot2_f32_f16 v51, v57, v21, v51\n\t"
    "v_dot2_f32_f16 v52, v67, v31, v52\n\t"
    "v_dot2_f32_f16 v44, v58, v12, v44\n\t"
    "v_dot2_f32_f16 v51, v58, v22, v51\n\t"
    "v_dot2_f32_f16 v52, v68, v32, v52\n\t"
    "v_dot2_f32_f16 v44, v59, v13, v44\n\t"
    "v_dot2_f32_f16 v51, v59, v23, v51\n\t"
    "v_dot2_f32_f16 v52, v69, v33, v52\n\t"
    "v_dot2_f32_f16 v44, v60, v14, v44\n\t"
    "v_dot2_f32_f16 v51, v60, v24, v51\n\t"
    "v_dot2_f32_f16 v52, v70, v34, v52\n\t"
    "v_dot2_f32_f16 v44, v61, v15, v44\n\t"
    "v_dot2_f32_f16 v51, v61, v25, v51\n\t"
    "v_dot2_f32_f16 v52, v71, v35, v52\n\t"
    "v_dot2_f32_f16 v44, v62, v16, v44\n\t"
    "v_dot2_f32_f16 v51, v62, v26, v51\n\t"
    "v_dot2_f32_f16 v52, v72, v36, v52\n\t"
    "v_dot2_f32_f16 v44, v63, v17, v44\n\t"
    "v_dot2_f32_f16 v51, v63, v27, v51\n\t"
    "v_dot2_f32_f16 v52, v73, v37, v52\n\t"
    "v_dot2_f32_f16 v44, v64, v18, v44\n\t"
    "v_dot2_f32_f16 v51, v64, v28, v51\n\t"
    "v_dot2_f32_f16 v52, v74, v38, v52\n\t"
    "v_dot2_f32_f16 v44, v65, v19, v44\n\t"
    "v_dot2_f32_f16 v51, v65, v29, v51\n\t"
    "v_dot2_f32_f16 v52, v75, v39, v52\n\t"
    "s_waitcnt vmcnt(1)\n\t"               // mx(2k+2) in v43
    "v_add_f32 v45, v43, v44\n\t"
    "v_add_f32 v53, v51, v52\n\t"
    "v_mul_f32 v45, 0xbfb8aa3b, v45\n\t"
    "v_mul_f32 v53, 0xbfb8aa3b, v53\n\t"
    "v_exp_f32 v45, v45\n\t"
    "v_exp_f32 v53, v53\n\t"
    "v_add_f32 v45, 1.0, v45\n\t"
    "v_add_f32 v53, 1.0, v53\n\t"
    "v_rcp_f32 v45, v45\n\t"
    "v_rcp_f32 v53, v53\n\t"
    "ds_bpermute_b32 v46, %[a1], v45\n\t"
    "ds_bpermute_b32 v54, %[a1], v53\n\t"
    "s_mul_i32 s66, s68, 240\n\t"
    "v_add_u32 v50, s66, %[jc4]\n\t"
    "s_waitcnt lgkmcnt(0)\n\t"
    "v_fma_f32 v47, v46, v44, v43\n\t"     // hp1, last v43 use
    "v_fma_f32 v55, v54, v52, v51\n\t"     // hp2
    "global_load_dword v43, v50, %[tabp]\n\t"  // mx(2k+4)
    "s_min_u32 s69, s69, 392\n\t"
    "s_load_dword s68, %[xp], s69\n\t"     // idx(2k+6)
    "s_add_u32 s69, s69, 8\n\t"
    "v_mul_f32 v47, 0x4038aa3b, v47\n\t"
    "v_mul_f32 v55, 0x4038aa3b, v55\n\t"
    "v_exp_f32 v47, v47\n\t"
    "v_exp_f32 v55, v55\n\t"
    "v_add_f32 v47, 1.0, v47\n\t"
    "v_add_f32 v55, 1.0, v55\n\t"
    "v_rcp_f32 v47, v47\n\t"
    "v_rcp_f32 v55, v55\n\t"
    "s_nop 0\n\t"
    "v_fma_f32 v47, -2.0, v47, 1.0\n\t"
    "v_fma_f32 v55, -2.0, v55, 1.0\n\t"
    "ds_bpermute_b32 v46, %[a2], v47\n\t"
    "ds_bpermute_b32 v54, %[a2], v55\n\t"
    "s_waitcnt lgkmcnt(0)\n\t"
    "v_sub_f32 v48, v40, v46\n\t"
    "v_fma_f32 v40, v45, v48, v46\n\t"     // h1(2k+2)
    "v_sub_f32 v48, v41, v54\n\t"
    "v_fma_f32 v41, v53, v48, v54\n\t"     // h2(2k+1)
    "v_cvt_f16_f32 v46, v40\n\t"
    "v_cvt_f16_f32 v54, v41\n\t"
    "ds_write_b16 %[wad], v46\n\t"
    "ds_write_b16 %[wad], v54 offset:128\n\t"
    "ds_read_b128 v[56:59], %[rad]\n\t"
    "ds_read_b128 v[60:63], %[rad] offset:16\n\t"
    "ds_read_b64  v[64:65], %[rad] offset:32\n\t"
    "ds_read_b128 v[66:69], %[rad] offset:128\n\t"
    "ds_read_b128 v[70:73], %[rad] offset:144\n\t"
    "ds_read_b64  v[74:75], %[rad] offset:160\n\t"
    "s_sub_u32 s67, s67, 1\n\t"
    "s_cmp_lg_u32 s67, 0\n\t"
    "s_cbranch_scc1 0b\n\t"
    "s_waitcnt vmcnt(0) lgkmcnt(0)\n\t"
    "v_mov_b32 %[h2o], v41\n\t"
    : [h2o] "=v"(h2out)
    : [wsp] "s"(ws), [xp] "s"(xr), [tabp] "s"(tab),
      [o1] "v"(o1), [jc4] "v"(jc4), [a1] "v"(a1), [a2] "v"(a2),
      [br1] "v"(br1), [bi2] "v"(bi2), [br2] "v"(br2),
      [wad] "v"(wad), [rad] "v"(rad)
    : "memory", "vcc", "scc",
      "v10","v11","v12","v13","v14","v15","v16","v17","v18","v19",
      "v20","v21","v22","v23","v24","v25","v26","v27","v28","v29",
      "v30","v31","v32","v33","v34","v35","v36","v37","v38","v39",
      "v40","v41","v42","v43","v44","v45","v46","v47","v48","v50",
      "v51","v52","v53","v54","v55",
      "v56","v57","v58","v59","v60","v61","v62","v63","v64","v65",
      "v66","v67","v68","v69","v70","v71","v72","v73","v74","v75",
      "s64","s65","s66","s67","s68","s69");

  // ---- dense: logits = h2 @ Wd + bd (h2 master fp32 in lanes 0..19) ----
  if (j < 15) {
    float a = ws[OFF_BD + j];
#pragma unroll
    for (int k = 0; k < HID; ++k)
      a = fmaf(rdl(h2out, k), ws[OFF_WD + k * 15 + j], a);
    if (isf) ((float*)out)[(size_t)e * 15 + j] = a;
    else ((__hip_bfloat16*)out)[(size_t)e * 15 + j] = __float2bfloat16(a);
  }
}

extern "C" void kernel_launch(void* const* d_in, const int* in_sizes, int n_in,
                              void* d_out, int out_size, void* d_ws, size_t ws_size,
                              hipStream_t stream) {
  const int* x    = (const int*)d_in[0];
  const void* emb = d_in[1];
  const void* W1  = d_in[2];
  const void* U1  = d_in[3];
  const void* b1  = d_in[4];
  const void* W2  = d_in[5];
  const void* U2  = d_in[6];
  const void* b2  = d_in[7];
  const void* Wd  = d_in[8];
  const void* bd  = d_in[9];
  float* ws = (float*)d_ws;   // 12,016,640 B used (proven safe)

  build_table<<<BBLK, 256, 0, stream>>>(
      emb, W1, b1, U1, W2, U2, b2, Wd, bd, ws);
  gru_main<<<2048, 256, 0, stream>>>(x, ws, emb, d_out);
}

// Round 10
// 197.658 us; speedup vs baseline: 1.4676x; 1.0132x over previous
//
#include <hip/hip_runtime.h>
#include <hip/hip_bf16.h>
#include <hip/hip_fp16.h>

#define SEQ_T 100
#define HID 20
#define EMB_D 50
#define VOCAB_N 50000
#define TABW 60          // tab row stride = 60 gate cols [z20|r20|h20]
#define NTILE 3125       // VOCAB_N/16
#define BBLK 782         // build_table blocks (x4 waves, 1 tile/wave)

typedef short sh8 __attribute__((ext_vector_type(8)));   // 8 bf16 bit patterns
typedef float f4  __attribute__((ext_vector_type(4)));

// ws layout (float/dword offsets). tab now f16: 50000*60*2B = 6 MB.
#define OFF_U1P 0        // 600 dwords (60 cols x 10 packed f16 k-pairs, PRESCALED)
#define OFF_W2P 600
#define OFF_U2P 1200
#define OFF_B1  3600     // 120 fp32 (first 60 raw bi1 for build MFMA; last 60 br1 prescaled)
#define OFF_B2  3720     // 120 fp32 (all prescaled)
#define OFF_WD  3840     // 300 fp32
#define OFF_BD  4140     // 15 fp32
#define OFF_TAB 4160     // 50000 x 60 f16 (PRESCALED: zr cols x -log2e, h cols x 2log2e)

__device__ __forceinline__ float ldf(const void* p, int i, int isf) {
  return isf ? ((const float*)p)[i]
             : __bfloat162float(((const __hip_bfloat16*)p)[i]);
}
__device__ __forceinline__ short f2bf(float f) {   // RNE fp32->bf16 bits
  unsigned u = __float_as_uint(f);
  u += 0x7fffu + ((u >> 16) & 1u);
  return (short)(u >> 16);
}
__device__ __forceinline__ float rdl(float v, int l) {
  return __uint_as_float(__builtin_amdgcn_readlane(__float_as_uint(v), l));
}
__device__ __forceinline__ int detect_isf(const void* emb) {
  uint4 dv = ((const uint4*)emb)[threadIdx.x & 63];
  int big = 0;
#pragma unroll
  for (int i = 0; i < 4; ++i) {
    unsigned w = ((const unsigned*)&dv)[i];
    big |= (((w >> 7) & 0xFF) >= 140) | (((w >> 23) & 0xFF) >= 140);
  }
  return (__ballot(big) != 0ull) ? 1 : 0;
}
// gate scale: zr cols (0-39) -log2e, h cols (40-59) +2log2e. ROUND-24: the
// sigmoid/tanh scale muls are folded into mx (f32 mul at tab store, exact)
// and mh (f16 weight prescale, ~2^-11 perturbation) -> 4 v_mul/half removed.
__device__ __forceinline__ float gsc(int col) {
  return (col < 40) ? -1.44269504f : 2.88539008f;
}

// tab = (emb @ W1 + bi1) * gsc, stored f16 (round-13 MFMA structure, verified).
__global__ __launch_bounds__(256) void build_table(
    const void* __restrict__ emb, const void* __restrict__ W1,
    const void* __restrict__ b1,
    const void* __restrict__ U1, const void* __restrict__ W2,
    const void* __restrict__ U2, const void* __restrict__ b2,
    const void* __restrict__ Wd, const void* __restrict__ bd,
    float* __restrict__ ws)
{
  const int isf = detect_isf(emb);
  if (blockIdx.x == 0) {                     // fold: weight prep
    const int t = threadIdx.x;
    unsigned* wsu = (unsigned*)ws;
    for (int i = t; i < 600; i += 256) {
      const int j = i / 10, p = i % 10;
      const int k0 = 2 * p, k1 = 2 * p + 1;
      const float s = gsc(j);
#define PK(M) ((unsigned)__half_as_ushort(__float2half_rn(ldf(M, k0 * 60 + j, isf) * s)) | \
               ((unsigned)__half_as_ushort(__float2half_rn(ldf(M, k1 * 60 + j, isf) * s)) << 16))
      wsu[OFF_U1P + i] = PK(U1);
      wsu[OFF_W2P + i] = PK(W2);
      wsu[OFF_U2P + i] = PK(U2);
#undef PK
    }
    for (int i = t; i < 120; i += 256) {
      // b1: first 60 raw (build MFMA C-init); last 60 (br1) prescaled.
      ws[OFF_B1 + i] = ldf(b1, i, isf) * (i >= 60 ? gsc(i - 60) : 1.f);
      // b2: both halves are gru dot-chain C-inits -> prescale by column.
      ws[OFF_B2 + i] = ldf(b2, i, isf) * gsc(i % 60);
    }
    for (int i = t; i < 300; i += 256) ws[OFF_WD + i] = ldf(Wd, i, isf);
    for (int i = t; i < 15;  i += 256) ws[OFF_BD + i] = ldf(bd, i, isf);
  }

  const int L = threadIdx.x & 63, q = L >> 4, c = L & 15;
  const int wid = blockIdx.x * 4 + (threadIdx.x >> 6);
  unsigned short* __restrict__ tab16 = (unsigned short*)(ws + OFF_TAB);

  __shared__ int4 sB[64][8];
  if (threadIdx.x < 64) {
#pragma unroll
    for (int nt = 0; nt < 4; ++nt) {
      const int col = nt * 16 + c;
      sh8 B0, B1;
#pragma unroll
      for (int jj = 0; jj < 8; ++jj) {
        const int k0 = q * 8 + jj, k1 = 32 + q * 8 + jj;
        B0[jj] = (col < TABW) ? f2bf(ldf(W1, k0 * TABW + col, isf)) : (short)0;
        B1[jj] = (col < TABW && k1 < EMB_D)
                     ? f2bf(ldf(W1, k1 * TABW + col, isf)) : (short)0;
      }
      sB[L][nt * 2]     = *(const int4*)&B0;
      sB[L][nt * 2 + 1] = *(const int4*)&B1;
    }
  }
  float bi[4];
#pragma unroll
  for (int nt = 0; nt < 4; ++nt) {
    const int col = nt * 16 + c;
    bi[nt] = (col < TABW) ? ldf(b1, col, isf) : 0.f;
  }
  __syncthreads();

  for (int tile = wid; tile < NTILE; tile += BBLK * 4) {
    const int v0 = tile * 16;
    sh8 A0, A1;
#pragma unroll
    for (int jj = 0; jj < 8; ++jj) { A0[jj] = 0; A1[jj] = 0; }
    if (!isf) {
      const unsigned short* eb = (const unsigned short*)emb;
      const size_t rb = (size_t)(v0 + c) * EMB_D;
#pragma unroll
      for (int i = 0; i < 4; ++i) {
        unsigned d = *(const unsigned*)(eb + rb + q * 8 + 2 * i);
        A0[2 * i] = (short)(d & 0xffff); A0[2 * i + 1] = (short)(d >> 16);
      }
      const int k1b = 32 + q * 8;
#pragma unroll
      for (int i = 0; i < 4; ++i) {
        const int k = k1b + 2 * i;
        if (k + 1 < EMB_D) {
          unsigned d = *(const unsigned*)(eb + rb + k);
          A1[2 * i] = (short)(d & 0xffff); A1[2 * i + 1] = (short)(d >> 16);
        }
      }
    } else {
      const float* ef = (const float*)emb;
      const size_t rb = (size_t)(v0 + c) * EMB_D;
#pragma unroll
      for (int jj = 0; jj < 8; ++jj) {
        const int k0 = q * 8 + jj, k1 = 32 + q * 8 + jj;
        A0[jj] = f2bf(ef[rb + k0]);
        A1[jj] = (k1 < EMB_D) ? f2bf(ef[rb + k1]) : (short)0;
      }
    }
#pragma unroll
    for (int nt = 0; nt < 4; ++nt) {
      int4 b0i = sB[L][nt * 2], b1i = sB[L][nt * 2 + 1];
      sh8 B0 = *(const sh8*)&b0i, B1 = *(const sh8*)&b1i;
      const int col = nt * 16 + c;
      f4 acc = { bi[nt], bi[nt], bi[nt], bi[nt] };
      acc = __builtin_amdgcn_mfma_f32_16x16x32_bf16(A0, B0, acc, 0, 0, 0);
      acc = __builtin_amdgcn_mfma_f32_16x16x32_bf16(A1, B1, acc, 0, 0, 0);
      if (col < TABW) {
        const float s = gsc(col);
#pragma unroll
        for (int r = 0; r < 4; ++r)
          tab16[(size_t)(v0 + q * 4 + r) * TABW + col] =
              __half_as_ushort(__float2half_rn(acc[r] * s));
      }
    }
  }
}

// ONE batch element per wave; 100-step GRU in inline asm (r22 structure).
// ROUND-24: (1) launch_bounds (256,6)->(256,5): the 6-wave cap forced ~6MB
// scratch spills (r23 WRITE_SIZE 6656KB) -- 5 waves = 102 VGPR cap, no
// spill. (2) gate-scale prescale (see gsc) removes 4 v_mul/half. (3) tab
// f16: row 120B (2 cache lines/gather, FETCH ~halved), +1 v_cvt/half.
// 59 -> 56 VALU per half; numerics shift ~1e-5 (f16 mx round).
__global__ __launch_bounds__(256, 5) void gru_main(
    const int* __restrict__ x, const float* __restrict__ ws,
    const void* __restrict__ emb, void* __restrict__ out)
{
  const int isf = detect_isf(emb);   // output dtype only
  const int j = threadIdx.x & 63;
  const int e = __builtin_amdgcn_readfirstlane(blockIdx.x * 4 + (threadIdx.x >> 6));
  const int jc = j < TABW ? j : 0;

  const int* xr = x + (size_t)e * SEQ_T;
  const unsigned short* tab = (const unsigned short*)(ws + OFF_TAB);
  const int o1 = jc * 40;                    // 10 packed dwords per column
  const int jc2 = jc * 2;                    // byte offset of col jc in f16 tab row
  const int a1 = ((j - 20) & 63) * 4;        // bpermute addr: r -> h-lanes
  const int a2 = ((j + 40) & 63) * 4;        // bpermute addr: hc -> z-lanes
  const float br1 = ws[OFF_B1 + 60 + jc];    // prescaled
  const float bi2 = ws[OFF_B2 + jc];         // prescaled
  const float br2 = ws[OFF_B2 + 60 + jc];    // prescaled

  // per-wave LDS h-broadcast buffers: h1 at +0 (128B), h2 at +128 (128B).
  __shared__ char sbuf[1024];
  const unsigned lb = (unsigned)(uintptr_t)&sbuf[0] + (threadIdx.x >> 6) * 256;
  const int wad = (int)(lb + (j < 20 ? 2 * j : 40 + 2 * (j - 20)));
  const int rad = (int)lb;
  float h2out;

  asm volatile(
    // ---- packed f16 weights: U1P v10-19, W2P v20-29, U2P v30-39 ----
    "global_load_dwordx4 v[10:13], %[o1], %[wsp] offset:0\n\t"
    "global_load_dwordx4 v[14:17], %[o1], %[wsp] offset:16\n\t"
    "global_load_dwordx2 v[18:19], %[o1], %[wsp] offset:32\n\t"
    "v_add_u32 v44, 0x960, %[o1]\n\t"
    "v_add_u32 v45, 0x12c0, %[o1]\n\t"
    "global_load_dwordx4 v[20:23], v44, %[wsp] offset:0\n\t"
    "global_load_dwordx4 v[24:27], v44, %[wsp] offset:16\n\t"
    "global_load_dwordx2 v[28:29], v44, %[wsp] offset:32\n\t"
    "global_load_dwordx4 v[30:33], v45, %[wsp] offset:0\n\t"
    "global_load_dwordx4 v[34:37], v45, %[wsp] offset:16\n\t"
    "global_load_dwordx2 v[38:39], v45, %[wsp] offset:32\n\t"
    // ---- h masters + h2 pair regs zero ----
    "v_mov_b32 v40, 0\n\t"
    "v_mov_b32 v41, 0\n\t"
    "v_mov_b32 v66, 0\n\tv_mov_b32 v67, 0\n\t"
    "v_mov_b32 v68, 0\n\tv_mov_b32 v69, 0\n\t"
    "v_mov_b32 v70, 0\n\tv_mov_b32 v71, 0\n\t"
    "v_mov_b32 v72, 0\n\tv_mov_b32 v73, 0\n\t"
    "v_mov_b32 v74, 0\n\tv_mov_b32 v75, 0\n\t"
    // ---- prime: mx0->v52, mx1->v42, mx2->v43 (raw f16); idx3/4->s65/s68 --
    "s_load_dword s65, %[xp], 0x0\n\t"
    "s_load_dword s66, %[xp], 0x4\n\t"
    "s_load_dword s68, %[xp], 0x8\n\t"
    "s_waitcnt lgkmcnt(0)\n\t"
    "s_mul_i32 s65, s65, 120\n\t"
    "s_mul_i32 s66, s66, 120\n\t"
    "s_mul_i32 s68, s68, 120\n\t"
    "v_add_u32 v50, s65, %[jc2]\n\t"
    "global_load_ushort v52, v50, %[tabp]\n\t"
    "v_add_u32 v50, s66, %[jc2]\n\t"
    "global_load_ushort v42, v50, %[tabp]\n\t"
    "v_add_u32 v50, s68, %[jc2]\n\t"
    "global_load_ushort v43, v50, %[tabp]\n\t"
    "s_load_dword s65, %[xp], 0xc\n\t"     // idx3 (odd stream)
    "s_load_dword s68, %[xp], 0x10\n\t"    // idx4 (even stream)
    "s_movk_i32 s64, 0x14\n\t"             // next odd x-offset (idx5)
    "s_movk_i32 s69, 0x18\n\t"             // next even x-offset (idx6)
    "s_movk_i32 s67, 0x32\n\t"             // 50 unrolled iterations
    "s_waitcnt vmcnt(2)\n\t"               // weights + mx0 ready
    "v_cvt_f32_f16 v52, v52\n\t"           // mx0 -> f32 (prescaled)
    // ======== PROLOGUE: L1(0)  (h1(-1)=0 -> mh = br1'; mx0 = v52) ========
    "v_mov_b32 v44, %[br1]\n\t"
    "v_add_f32 v45, v52, v44\n\t"
    "v_exp_f32 v45, v45\n\t"
    "s_nop 1\n\t"
    "v_add_f32 v45, 1.0, v45\n\t"
    "v_rcp_f32 v45, v45\n\t"
    "s_nop 1\n\t"
    "ds_bpermute_b32 v46, %[a1], v45\n\t"
    "s_waitcnt lgkmcnt(0)\n\t"
    "v_fma_f32 v47, v46, v44, v52\n\t"
    "v_exp_f32 v47, v47\n\t"
    "s_nop 1\n\t"
    "v_add_f32 v47, 1.0, v47\n\t"
    "v_rcp_f32 v47, v47\n\t"
    "s_nop 1\n\t"
    "v_fma_f32 v47, -2.0, v47, 1.0\n\t"
    "ds_bpermute_b32 v46, %[a2], v47\n\t"
    "s_waitcnt lgkmcnt(0)\n\t"
    "v_sub_f32 v48, v40, v46\n\t"
    "v_fma_f32 v40, v45, v48, v46\n\t"     // h1(0)
    "v_cvt_f16_f32 v46, v40\n\t"
    "ds_write_b16 %[wad], v46\n\t"
    "ds_read_b128 v[56:59], %[rad]\n\t"
    "ds_read_b128 v[60:63], %[rad] offset:16\n\t"
    "ds_read_b64  v[64:65], %[rad] offset:32\n\t"
    // ======== LOOP k=0..49 ========
    "0:\n\t"
    // ---- HALF A: L2(2k) || L1(2k+1). h1(2k)=v56-65, h2(2k-1)=v66-75.
    "s_waitcnt lgkmcnt(0)\n\t"             // h pair reads done
    "v_dot2_f32_f16 v44, v56, v10, %[br1]\n\t"
    "v_dot2_f32_f16 v51, v56, v20, %[bi2]\n\t"
    "v_dot2_f32_f16 v52, v66, v30, %[br2]\n\t"
    "v_dot2_f32_f16 v44, v57, v11, v44\n\t"
    "v_dot2_f32_f16 v51, v57, v21, v51\n\t"
    "v_dot2_f32_f16 v52, v67, v31, v52\n\t"
    "v_dot2_f32_f16 v44, v58, v12, v44\n\t"
    "v_dot2_f32_f16 v51, v58, v22, v51\n\t"
    "v_dot2_f32_f16 v52, v68, v32, v52\n\t"
    "v_dot2_f32_f16 v44, v59, v13, v44\n\t"
    "v_dot2_f32_f16 v51, v59, v23, v51\n\t"
    "v_dot2_f32_f16 v52, v69, v33, v52\n\t"
    "v_dot2_f32_f16 v44, v60, v14, v44\n\t"
    "v_dot2_f32_f16 v51, v60, v24, v51\n\t"
    "v_dot2_f32_f16 v52, v70, v34, v52\n\t"
    "v_dot2_f32_f16 v44, v61, v15, v44\n\t"
    "v_dot2_f32_f16 v51, v61, v25, v51\n\t"
    "v_dot2_f32_f16 v52, v71, v35, v52\n\t"
    "v_dot2_f32_f16 v44, v62, v16, v44\n\t"
    "v_dot2_f32_f16 v51, v62, v26, v51\n\t"
    "v_dot2_f32_f16 v52, v72, v36, v52\n\t"
    "v_dot2_f32_f16 v44, v63, v17, v44\n\t"
    "v_dot2_f32_f16 v51, v63, v27, v51\n\t"
    "v_dot2_f32_f16 v52, v73, v37, v52\n\t"
    "v_dot2_f32_f16 v44, v64, v18, v44\n\t"
    "v_dot2_f32_f16 v51, v64, v28, v51\n\t"
    "v_dot2_f32_f16 v52, v74, v38, v52\n\t"
    "v_dot2_f32_f16 v44, v65, v19, v44\n\t"
    "v_dot2_f32_f16 v51, v65, v29, v51\n\t"
    "v_dot2_f32_f16 v52, v75, v39, v52\n\t"
    "s_waitcnt vmcnt(1)\n\t"               // mx(2k+1) raw f16 in v42
    "v_cvt_f32_f16 v42, v42\n\t"
    "v_add_f32 v45, v42, v44\n\t"
    "v_add_f32 v53, v51, v52\n\t"
    "v_exp_f32 v45, v45\n\t"
    "v_exp_f32 v53, v53\n\t"
    "v_add_f32 v45, 1.0, v45\n\t"
    "v_add_f32 v53, 1.0, v53\n\t"
    "v_rcp_f32 v45, v45\n\t"
    "v_rcp_f32 v53, v53\n\t"
    "ds_bpermute_b32 v46, %[a1], v45\n\t"
    "ds_bpermute_b32 v54, %[a1], v53\n\t"
    "s_mul_i32 s66, s65, 120\n\t"
    "v_add_u32 v50, s66, %[jc2]\n\t"
    "s_waitcnt lgkmcnt(0)\n\t"
    "v_fma_f32 v47, v46, v44, v42\n\t"     // hp1, last v42 use
    "v_fma_f32 v55, v54, v52, v51\n\t"     // hp2
    "global_load_ushort v42, v50, %[tabp]\n\t"  // mx(2k+3)
    "s_min_u32 s64, s64, 396\n\t"
    "s_load_dword s65, %[xp], s64\n\t"     // idx(2k+5)
    "s_add_u32 s64, s64, 8\n\t"
    "v_exp_f32 v47, v47\n\t"
    "v_exp_f32 v55, v55\n\t"
    "v_add_f32 v47, 1.0, v47\n\t"
    "v_add_f32 v55, 1.0, v55\n\t"
    "v_rcp_f32 v47, v47\n\t"
    "v_rcp_f32 v55, v55\n\t"
    "s_nop 0\n\t"
    "v_fma_f32 v47, -2.0, v47, 1.0\n\t"    // hc1
    "v_fma_f32 v55, -2.0, v55, 1.0\n\t"    // hc2
    "ds_bpermute_b32 v46, %[a2], v47\n\t"
    "ds_bpermute_b32 v54, %[a2], v55\n\t"
    "s_waitcnt lgkmcnt(0)\n\t"
    "v_sub_f32 v48, v40, v46\n\t"
    "v_fma_f32 v40, v45, v48, v46\n\t"     // h1(2k+1)
    "v_sub_f32 v48, v41, v54\n\t"
    "v_fma_f32 v41, v53, v48, v54\n\t"     // h2(2k)
    "v_cvt_f16_f32 v46, v40\n\t"
    "v_cvt_f16_f32 v54, v41\n\t"
    "ds_write_b16 %[wad], v46\n\t"
    "ds_write_b16 %[wad], v54 offset:128\n\t"
    "ds_read_b128 v[56:59], %[rad]\n\t"
    "ds_read_b128 v[60:63], %[rad] offset:16\n\t"
    "ds_read_b64  v[64:65], %[rad] offset:32\n\t"
    "ds_read_b128 v[66:69], %[rad] offset:128\n\t"
    "ds_read_b128 v[70:73], %[rad] offset:144\n\t"
    "ds_read_b64  v[74:75], %[rad] offset:160\n\t"
    // ---- HALF B: L2(2k+1) || L1(2k+2). h1(2k+1)=v56-65, h2(2k)=v66-75.
    "s_waitcnt lgkmcnt(0)\n\t"
    "v_dot2_f32_f16 v44, v56, v10, %[br1]\n\t"
    "v_dot2_f32_f16 v51, v56, v20, %[bi2]\n\t"
    "v_dot2_f32_f16 v52, v66, v30, %[br2]\n\t"
    "v_dot2_f32_f16 v44, v57, v11, v44\n\t"
    "v_dot2_f32_f16 v51, v57, v21, v51\n\t"
    "v_dot2_f32_f16 v52, v67, v31, v52\n\t"
    "v_dot2_f32_f16 v44, v58, v12, v44\n\t"
    "v_dot2_f32_f16 v51, v58, v22, v51\n\t"
    "v_dot2_f32_f16 v52, v68, v32, v52\n\t"
    "v_dot2_f32_f16 v44, v59, v13, v44\n\t"
    "v_dot2_f32_f16 v51, v59, v23, v51\n\t"
    "v_dot2_f32_f16 v52, v69, v33, v52\n\t"
    "v_dot2_f32_f16 v44, v60, v14, v44\n\t"
    "v_dot2_f32_f16 v51, v60, v24, v51\n\t"
    "v_dot2_f32_f16 v52, v70, v34, v52\n\t"
    "v_dot2_f32_f16 v44, v61, v15, v44\n\t"
    "v_dot2_f32_f16 v51, v61, v25, v51\n\t"
    "v_dot2_f32_f16 v52, v71, v35, v52\n\t"
    "v_dot2_f32_f16 v44, v62, v16, v44\n\t"
    "v_dot2_f32_f16 v51, v62, v26, v51\n\t"
    "v_dot2_f32_f16 v52, v72, v36, v52\n\t"
    "v_dot2_f32_f16 v44, v63, v17, v44\n\t"
    "v_dot2_f32_f16 v51, v63, v27, v51\n\t"
    "v_dot2_f32_f16 v52, v73, v37, v52\n\t"
    "v_dot2_f32_f16 v44, v64, v18, v44\n\t"
    "v_dot2_f32_f16 v51, v64, v28, v51\n\t"
    "v_dot2_f32_f16 v52, v74, v38, v52\n\t"
    "v_dot2_f32_f16 v44, v65, v19, v44\n\t"
    "v_dot2_f32_f16 v51, v65, v29, v51\n\t"
    "v_dot2_f32_f16 v52, v75, v39, v52\n\t"
    "s_waitcnt vmcnt(1)\n\t"               // mx(2k+2) raw f16 in v43
    "v_cvt_f32_f16 v43, v43\n\t"
    "v_add_f32 v45, v43, v44\n\t"
    "v_add_f32 v53, v51, v52\n\t"
    "v_exp_f32 v45, v45\n\t"
    "v_exp_f32 v53, v53\n\t"
    "v_add_f32 v45, 1.0, v45\n\t"
    "v_add_f32 v53, 1.0, v53\n\t"
    "v_rcp_f32 v45, v45\n\t"
    "v_rcp_f32 v53, v53\n\t"
    "ds_bpermute_b32 v46, %[a1], v45\n\t"
    "ds_bpermute_b32 v54, %[a1], v53\n\t"
    "s_mul_i32 s66, s68, 120\n\t"
    "v_add_u32 v50, s66, %[jc2]\n\t"
    "s_waitcnt lgkmcnt(0)\n\t"
    "v_fma_f32 v47, v46, v44, v43\n\t"     // hp1, last v43 use
    "v_fma_f32 v55, v54, v52, v51\n\t"     // hp2
    "global_load_ushort v43, v50, %[tabp]\n\t"  // mx(2k+4)
    "s_min_u32 s69, s69, 392\n\t"
    "s_load_dword s68, %[xp], s69\n\t"     // idx(2k+6)
    "s_add_u32 s69, s69, 8\n\t"
    "v_exp_f32 v47, v47\n\t"
    "v_exp_f32 v55, v55\n\t"
    "v_add_f32 v47, 1.0, v47\n\t"
    "v_add_f32 v55, 1.0, v55\n\t"
    "v_rcp_f32 v47, v47\n\t"
    "v_rcp_f32 v55, v55\n\t"
    "s_nop 0\n\t"
    "v_fma_f32 v47, -2.0, v47, 1.0\n\t"
    "v_fma_f32 v55, -2.0, v55, 1.0\n\t"
    "ds_bpermute_b32 v46, %[a2], v47\n\t"
    "ds_bpermute_b32 v54, %[a2], v55\n\t"
    "s_waitcnt lgkmcnt(0)\n\t"
    "v_sub_f32 v48, v40, v46\n\t"
    "v_fma_f32 v40, v45, v48, v46\n\t"     // h1(2k+2)
    "v_sub_f32 v48, v41, v54\n\t"
    "v_fma_f32 v41, v53, v48, v54\n\t"     // h2(2k+1)
    "v_cvt_f16_f32 v46, v40\n\t"
    "v_cvt_f16_f32 v54, v41\n\t"
    "ds_write_b16 %[wad], v46\n\t"
    "ds_write_b16 %[wad], v54 offset:128\n\t"
    "ds_read_b128 v[56:59], %[rad]\n\t"
    "ds_read_b128 v[60:63], %[rad] offset:16\n\t"
    "ds_read_b64  v[64:65], %[rad] offset:32\n\t"
    "ds_read_b128 v[66:69], %[rad] offset:128\n\t"
    "ds_read_b128 v[70:73], %[rad] offset:144\n\t"
    "ds_read_b64  v[74:75], %[rad] offset:160\n\t"
    "s_sub_u32 s67, s67, 1\n\t"
    "s_cmp_lg_u32 s67, 0\n\t"
    "s_cbranch_scc1 0b\n\t"
    "s_waitcnt vmcnt(0) lgkmcnt(0)\n\t"
    "v_mov_b32 %[h2o], v41\n\t"
    : [h2o] "=v"(h2out)
    : [wsp] "s"(ws), [xp] "s"(xr), [tabp] "s"(tab),
      [o1] "v"(o1), [jc2] "v"(jc2), [a1] "v"(a1), [a2] "v"(a2),
      [br1] "v"(br1), [bi2] "v"(bi2), [br2] "v"(br2),
      [wad] "v"(wad), [rad] "v"(rad)
    : "memory", "vcc", "scc",
      "v10","v11","v12","v13","v14","v15","v16","v17","v18","v19",
      "v20","v21","v22","v23","v24","v25","v26","v27","v28","v29",
      "v30","v31","v32","v33","v34","v35","v36","v37","v38","v39",
      "v40","v41","v42","v43","v44","v45","v46","v47","v48","v50",
      "v51","v52","v53","v54","v55",
      "v56","v57","v58","v59","v60","v61","v62","v63","v64","v65",
      "v66","v67","v68","v69","v70","v71","v72","v73","v74","v75",
      "s64","s65","s66","s67","s68","s69");

  // ---- dense: logits = h2 @ Wd + bd (h2 master fp32 in lanes 0..19) ----
  if (j < 15) {
    float a = ws[OFF_BD + j];
#pragma unroll
    for (int k = 0; k < HID; ++k)
      a = fmaf(rdl(h2out, k), ws[OFF_WD + k * 15 + j], a);
    if (isf) ((float*)out)[(size_t)e * 15 + j] = a;
    else ((__hip_bfloat16*)out)[(size_t)e * 15 + j] = __float2bfloat16(a);
  }
}

extern "C" void kernel_launch(void* const* d_in, const int* in_sizes, int n_in,
                              void* d_out, int out_size, void* d_ws, size_t ws_size,
                              hipStream_t stream) {
  const int* x    = (const int*)d_in[0];
  const void* emb = d_in[1];
  const void* W1  = d_in[2];
  const void* U1  = d_in[3];
  const void* b1  = d_in[4];
  const void* W2  = d_in[5];
  const void* U2  = d_in[6];
  const void* b2  = d_in[7];
  const void* Wd  = d_in[8];
  const void* bd  = d_in[9];
  float* ws = (float*)d_ws;   // 6.02 MB used (12 MB proven safe)

  build_table<<<BBLK, 256, 0, stream>>>(
      emb, W1, b1, U1, W2, U2, b2, Wd, bd, ws);
  gru_main<<<2048, 256, 0, stream>>>(x, ws, emb, d_out);
}